// Round 4
// baseline (640.356 us; speedup 1.0000x reference)
//
#include <hip/hip_runtime.h>
#include <hip/hip_bf16.h>
#include <stdint.h>
#include <math.h>

#define S_LEN 2048
#define DMODEL 1024
#define NHEAD 16
#define DHEAD 64
#define FFDIM 4096
#define NLAYER 2

using bf16 = __hip_bfloat16;
typedef __attribute__((ext_vector_type(8))) short bf16x8;
typedef __attribute__((ext_vector_type(4))) float f32x4;

#define MFMA16x16(A, B, C) __builtin_amdgcn_mfma_f32_16x16x32_bf16(A, B, C, 0, 0, 0)
#define EXP2(x) __builtin_amdgcn_exp2f(x)

__device__ __forceinline__ float bf2f(uint32_t u16bits) {
  union { uint32_t i; float f; } x;
  x.i = u16bits << 16;
  return x.f;
}
__device__ __forceinline__ uint16_t f2bf(float f) {
  return __builtin_bit_cast(uint16_t, __float2bfloat16(f));
}

// DPP 16-lane (row) reductions — VALU pipe, no LDS traffic.
template <int CTRL>
__device__ __forceinline__ float dppf(float x) {
  return __builtin_bit_cast(float,
      __builtin_amdgcn_update_dpp(0, __builtin_bit_cast(int, x), CTRL, 0xF, 0xF, true));
}
__device__ __forceinline__ float rowmax16(float x) {
  x = fmaxf(x, dppf<0xB1>(x));   // quad_perm xor1
  x = fmaxf(x, dppf<0x4E>(x));   // quad_perm xor2
  x = fmaxf(x, dppf<0x141>(x));  // row_half_mirror
  x = fmaxf(x, dppf<0x140>(x));  // row_mirror
  return x;
}
__device__ __forceinline__ float rowsum16(float x) {
  x += dppf<0xB1>(x);
  x += dppf<0x4E>(x);
  x += dppf<0x141>(x);
  x += dppf<0x140>(x);
  return x;
}

// ---------------------------------------------------------------------------
// Weight cast + transpose: in fp32 (R x C)  ->  out bf16 (C x R)
// ---------------------------------------------------------------------------
__global__ __launch_bounds__(256) void k_tcast(const float* __restrict__ in,
                                               bf16* __restrict__ out,
                                               int R, int C) {
  __shared__ float tl[32][33];
  int t = threadIdx.x;
  int r0 = blockIdx.y * 32, c0 = blockIdx.x * 32;
  int cl = t & 31, rl = t >> 5;
#pragma unroll
  for (int i = 0; i < 4; ++i)
    tl[rl + i * 8][cl] = in[(size_t)(r0 + rl + i * 8) * C + c0 + cl];
  __syncthreads();
#pragma unroll
  for (int i = 0; i < 4; ++i)
    out[(size_t)(c0 + rl + i * 8) * R + r0 + cl] = __float2bfloat16(tl[cl][rl + i * 8]);
}

// ---------------------------------------------------------------------------
// LayerNorm over DMODEL=1024
// ---------------------------------------------------------------------------
__device__ __forceinline__ void ln_store4(bf16* p, float a, float b, float c, float d) {
  uint2 u;
  u.x = (uint32_t)f2bf(a) | ((uint32_t)f2bf(b) << 16);
  u.y = (uint32_t)f2bf(c) | ((uint32_t)f2bf(d) << 16);
  *(uint2*)p = u;
}
__device__ __forceinline__ void ln_store4(float* p, float a, float b, float c, float d) {
  *(float4*)p = make_float4(a, b, c, d);
}

template <typename OUT>
__global__ __launch_bounds__(256) void k_ln(const float* __restrict__ h,
                                            const float* __restrict__ g,
                                            const float* __restrict__ b,
                                            OUT* __restrict__ y) {
  int row = blockIdx.x, t = threadIdx.x;
  const float4 v = ((const float4*)(h + (size_t)row * DMODEL))[t];
  float s = v.x + v.y + v.z + v.w;
  float s2 = v.x * v.x + v.y * v.y + v.z * v.z + v.w * v.w;
#pragma unroll
  for (int off = 32; off > 0; off >>= 1) {
    s += __shfl_down(s, off);
    s2 += __shfl_down(s2, off);
  }
  __shared__ float red[8];
  int w = t >> 6;
  if ((t & 63) == 0) { red[w] = s; red[4 + w] = s2; }
  __syncthreads();
  s = red[0] + red[1] + red[2] + red[3];
  s2 = red[4] + red[5] + red[6] + red[7];
  float mean = s * (1.0f / DMODEL);
  float var = s2 * (1.0f / DMODEL) - mean * mean;
  float rstd = rsqrtf(var + 1e-5f);
  float4 gv = ((const float4*)g)[t];
  float4 bv = ((const float4*)b)[t];
  float o0 = (v.x - mean) * rstd * gv.x + bv.x;
  float o1 = (v.y - mean) * rstd * gv.y + bv.y;
  float o2 = (v.z - mean) * rstd * gv.z + bv.z;
  float o3 = (v.w - mean) * rstd * gv.w + bv.w;
  ln_store4(y + (size_t)row * DMODEL + t * 4, o0, o1, o2, o3);
}

// ---------------------------------------------------------------------------
// RoPE on q,k sections of qkv
// ---------------------------------------------------------------------------
__global__ __launch_bounds__(256) void k_rope(const bf16* __restrict__ qkv,
                                              const float* __restrict__ fcos,
                                              const float* __restrict__ fsin,
                                              bf16* __restrict__ qr,
                                              bf16* __restrict__ kr) {
  int idx = blockIdx.x * 256 + threadIdx.x;
  int p = idx & 31;
  int hh = (idx >> 5) & (NHEAD - 1);
  int s = idx >> 9;
  float c = fcos[s * 32 + p], sn = fsin[s * 32 + p];
  int colq = hh * DHEAD + 2 * p;
  uint32_t rq = *(const uint32_t*)(qkv + (size_t)s * 3 * DMODEL + colq);
  uint32_t rk = *(const uint32_t*)(qkv + (size_t)s * 3 * DMODEL + DMODEL + colq);
  {
    float te = bf2f(rq & 0xffffu), to = bf2f(rq >> 16);
    uint32_t outv = (uint32_t)f2bf(te * c - to * sn) | ((uint32_t)f2bf(te * sn + to * c) << 16);
    *(uint32_t*)(qr + (size_t)s * DMODEL + colq) = outv;
  }
  {
    float te = bf2f(rk & 0xffffu), to = bf2f(rk >> 16);
    uint32_t outv = (uint32_t)f2bf(te * c - to * sn) | ((uint32_t)f2bf(te * sn + to * c) << 16);
    *(uint32_t*)(kr + (size_t)s * DMODEL + colq) = outv;
  }
}

// ---------------------------------------------------------------------------
// V transpose per head: vT[h][d][s]
// ---------------------------------------------------------------------------
__global__ __launch_bounds__(256) void k_tv(const bf16* __restrict__ qkv,
                                            bf16* __restrict__ vT) {
  __shared__ bf16 tl[64][65];
  int t = threadIdx.x;
  int hh = blockIdx.y;
  int sb = blockIdx.x * 64;
#pragma unroll
  for (int i = 0; i < 16; ++i) {
    int e = i * 256 + t;
    int sl = e >> 6, d = e & 63;
    tl[sl][d] = qkv[(size_t)(sb + sl) * 3 * DMODEL + 2 * DMODEL + hh * DHEAD + d];
  }
  __syncthreads();
#pragma unroll
  for (int i = 0; i < 16; ++i) {
    int e = i * 256 + t;
    int d = e >> 6, sl = e & 63;
    vT[(size_t)(hh * DHEAD + d) * S_LEN + sb + sl] = tl[sl][d];
  }
}

// ---------------------------------------------------------------------------
// GEMM: C[M,N] = A[M,K](bf16) * BT[N,K]^T + bias[N].
// EPI 0: bf16.  EPI 1: fp32 = res + acc + bias.  EPI 2: gelu -> bf16.
// BM x 128 tile, BK=32. BM=128: 4 waves x (64x64). BM=64: 4 waves x (32x64)
// (grid doubles -> fixes half-idle GPU on N=1024 GEMMs).
// ---------------------------------------------------------------------------
template <int EPI, int BM>
__global__ __launch_bounds__(256) void k_gemm_bt(const bf16* __restrict__ A,
                                                 const bf16* __restrict__ BT,
                                                 const float* __restrict__ bias,
                                                 const float* __restrict__ res,
                                                 void* __restrict__ out,
                                                 int M, int N, int K) {
  constexpr int MF = BM / 32;  // m-frags per wave
  __shared__ bf16 As[BM * 32];
  __shared__ bf16 Bs[128 * 32];
  int t = threadIdx.x;
  int w = t >> 6, l = t & 63, lr = l & 15, lg = l >> 4;
  int bm = blockIdx.x * BM, bn = blockIdx.y * 128;
  int wm = (w >> 1) * (BM / 2), wn = (w & 1) * 64;

  f32x4 zero4 = {0.f, 0.f, 0.f, 0.f};
  f32x4 acc[MF][4];
#pragma unroll
  for (int mf = 0; mf < MF; ++mf)
#pragma unroll
    for (int nf = 0; nf < 4; ++nf) acc[mf][nf] = zero4;

  for (int kt = 0; kt < K; kt += 32) {
    __syncthreads();
#pragma unroll
    for (int i = 0; i < BM / 64; ++i) {
      int chunk = i * 256 + t;
      int row = chunk >> 2, ko = (chunk & 3) * 8;
      __builtin_amdgcn_global_load_lds(
          (__attribute__((address_space(1))) void*)(A + (size_t)(bm + row) * K + kt + ko),
          (__attribute__((address_space(3))) void*)(As + chunk * 8), 16, 0, 0);
    }
#pragma unroll
    for (int i = 0; i < 2; ++i) {
      int chunk = i * 256 + t;
      int row = chunk >> 2, ko = (chunk & 3) * 8;
      __builtin_amdgcn_global_load_lds(
          (__attribute__((address_space(1))) void*)(BT + (size_t)(bn + row) * K + kt + ko),
          (__attribute__((address_space(3))) void*)(Bs + chunk * 8), 16, 0, 0);
    }
    __syncthreads();
    bf16x8 af[MF], bfr[4];
#pragma unroll
    for (int mf = 0; mf < MF; ++mf)
      af[mf] = *(const bf16x8*)(As + (wm + mf * 16 + lr) * 32 + lg * 8);
#pragma unroll
    for (int nf = 0; nf < 4; ++nf)
      bfr[nf] = *(const bf16x8*)(Bs + (wn + nf * 16 + lr) * 32 + lg * 8);
#pragma unroll
    for (int mf = 0; mf < MF; ++mf)
#pragma unroll
      for (int nf = 0; nf < 4; ++nf)
        acc[mf][nf] = MFMA16x16(af[mf], bfr[nf], acc[mf][nf]);
  }

  float* outf = (float*)out;
  bf16* outb = (bf16*)out;
#pragma unroll
  for (int mf = 0; mf < MF; ++mf) {
#pragma unroll
    for (int nf = 0; nf < 4; ++nf) {
      int col = bn + wn + nf * 16 + lr;
      float bv = bias[col];
      int row0 = bm + wm + mf * 16 + lg * 4;
#pragma unroll
      for (int r = 0; r < 4; ++r) {
        float v = acc[mf][nf][r] + bv;
        size_t idx = (size_t)(row0 + r) * N + col;
        if (EPI == 0) {
          outb[idx] = __float2bfloat16(v);
        } else if (EPI == 1) {
          outf[idx] = res[idx] + v;
        } else {
          float gl = 0.5f * v * (1.0f + tanhf(0.7978845608028654f * (v + 0.044715f * v * v * v)));
          outb[idx] = __float2bfloat16(gl);
        }
      }
    }
  }
}

// ---------------------------------------------------------------------------
// Flash attention v3. Split-K across 4 waves (512 keys each), KVBLK=128,
// softmax in exp2 domain, DPP row-reduce (no LDS shuffles), defer-max,
// XOR-swizzled per-wave P scratch, V prefetch, setprio around MFMA.
// Grid (NHEAD, S/16): block id % 8 == head % 8 -> per-XCD K/V L2 locality.
// ---------------------------------------------------------------------------
__global__ __launch_bounds__(256, 4) void k_attn(const bf16* __restrict__ qr,
                                                 const bf16* __restrict__ kr,
                                                 const bf16* __restrict__ vT,
                                                 const int* __restrict__ offs,
                                                 bf16* __restrict__ ao) {
  __shared__ char segs[S_LEN];
  __shared__ bf16 sP[4 * 16 * 128];  // per-wave [16][128], col ^= (row&3)<<4
  __shared__ float mM[4][16];
  __shared__ float lL[4][16];
  __shared__ float oO[4][16][68];
  int t = threadIdx.x, w = t >> 6, l = t & 63, lr = l & 15, lg = l >> 4;
  int hh = blockIdx.x, qb = blockIdx.y * 16;

  int o0 = offs[0], o1 = offs[1], o2 = offs[2], o3 = offs[3], o4 = offs[4];
  for (int p = t; p < S_LEN; p += 256)
    segs[p] = (char)((o0 <= p) + (o1 <= p) + (o2 <= p) + (o3 <= p) + (o4 <= p));
  __syncthreads();

  constexpr float LOG2E = 1.4426950408889634f;
  constexpr float C1 = 0.125f * LOG2E;

  const bf16* qp = qr + (size_t)(qb + lr) * DMODEL + hh * DHEAD + lg * 8;
  bf16x8 aq0 = *(const bf16x8*)(qp);
  bf16x8 aq1 = *(const bf16x8*)(qp + 32);

  bf16* sPw = sP + w * 2048;
  const bf16* vTh = vT + (size_t)hh * DHEAD * S_LEN;

  f32x4 zero4 = {0.f, 0.f, 0.f, 0.f};
  f32x4 accO[4];
  float m_r[4], l_p[4];
  int segq[4];
#pragma unroll
  for (int r = 0; r < 4; ++r) {
    accO[r] = zero4;
    m_r[r] = -1e30f;
    l_p[r] = 0.f;
    segq[r] = segs[qb + lg * 4 + r];
  }

  for (int it = 0; it < 4; ++it) {
    int j0 = w * 512 + it * 128;
    // ---- QK^T over 128 keys, two reg-batches of 4 key-frags ----
    f32x4 accS[8];
#pragma unroll
    for (int half = 0; half < 2; ++half) {
      bf16x8 kb0[4], kb1[4];
#pragma unroll
      for (int j = 0; j < 4; ++j) {
        int jf = half * 4 + j;
        const bf16* kp = kr + (size_t)(j0 + jf * 16 + lr) * DMODEL + hh * DHEAD + lg * 8;
        kb0[j] = *(const bf16x8*)(kp);
        kb1[j] = *(const bf16x8*)(kp + 32);
      }
      __builtin_amdgcn_s_setprio(1);
#pragma unroll
      for (int j = 0; j < 4; ++j) {
        accS[half * 4 + j] = MFMA16x16(aq0, kb0[j], zero4);
        accS[half * 4 + j] = MFMA16x16(aq1, kb1[j], accS[half * 4 + j]);
      }
      __builtin_amdgcn_s_setprio(0);
    }
    // ---- V prefetch (df=0) overlaps softmax ----
    bf16x8 v0[4];
#pragma unroll
    for (int ks = 0; ks < 4; ++ks)
      v0[ks] = *(const bf16x8*)(vTh + (size_t)lr * S_LEN + j0 + ks * 32 + lg * 8);
    // ---- scale + segment bias (exp2 domain) ----
    int sj[8];
#pragma unroll
    for (int jf = 0; jf < 8; ++jf) sj[jf] = segs[j0 + jf * 16 + lr];
#pragma unroll
    for (int jf = 0; jf < 8; ++jf)
#pragma unroll
      for (int r = 0; r < 4; ++r)
        accS[jf][r] = accS[jf][r] * C1 + ((segq[r] == sj[jf]) ? LOG2E : 0.0f);
    // ---- row max: 7 in-reg + 4 DPP steps ----
    float rmax[4];
#pragma unroll
    for (int r = 0; r < 4; ++r) {
      float a = fmaxf(fmaxf(accS[0][r], accS[1][r]), fmaxf(accS[2][r], accS[3][r]));
      float b = fmaxf(fmaxf(accS[4][r], accS[5][r]), fmaxf(accS[6][r], accS[7][r]));
      rmax[r] = rowmax16(fmaxf(a, b));
    }
    // ---- defer-max: rescale only when max grows by > 8 (log2) ----
    int need = 0;
#pragma unroll
    for (int r = 0; r < 4; ++r) need |= (rmax[r] > m_r[r] + 8.0f) ? 1 : 0;
    if (__any(need)) {
#pragma unroll
      for (int r = 0; r < 4; ++r) {
        float mnew = fmaxf(m_r[r], rmax[r]);
        float fs = EXP2(m_r[r] - mnew);
        m_r[r] = mnew;
        l_p[r] *= fs;
#pragma unroll
        for (int df = 0; df < 4; ++df) accO[df][r] *= fs;
      }
    }
    // ---- exp2 + P write (swizzled; row&3 == r, so offsets fold to imm) ----
#pragma unroll
    for (int jf = 0; jf < 8; ++jf)
#pragma unroll
      for (int r = 0; r < 4; ++r) {
        float pv = EXP2(accS[jf][r] - m_r[r]);
        l_p[r] += pv;
        sPw[(lg * 4 + r) * 128 + ((jf ^ r) * 16) + lr] = __float2bfloat16(pv);
      }
    asm volatile("s_waitcnt lgkmcnt(0)" ::: "memory");
    bf16x8 pa[4];
#pragma unroll
    for (int ks = 0; ks < 4; ++ks)
      pa[ks] = *(const bf16x8*)(sPw + lr * 128 + (((ks * 32 + lg * 8) ^ ((lr & 3) << 4))));
    // ---- remaining V loads, then PV MFMAs ----
    bf16x8 v123[3][4];
#pragma unroll
    for (int df = 1; df < 4; ++df)
#pragma unroll
      for (int ks = 0; ks < 4; ++ks)
        v123[df - 1][ks] =
            *(const bf16x8*)(vTh + (size_t)(df * 16 + lr) * S_LEN + j0 + ks * 32 + lg * 8);
    __builtin_amdgcn_s_setprio(1);
#pragma unroll
    for (int ks = 0; ks < 4; ++ks) accO[0] = MFMA16x16(pa[ks], v0[ks], accO[0]);
#pragma unroll
    for (int df = 1; df < 4; ++df)
#pragma unroll
      for (int ks = 0; ks < 4; ++ks)
        accO[df] = MFMA16x16(pa[ks], v123[df - 1][ks], accO[df]);
    __builtin_amdgcn_s_setprio(0);
    asm volatile("" ::: "memory");  // keep next iter's ds_writes after reads
  }

  // finalize l (per-lane partials -> row totals), publish partials
#pragma unroll
  for (int r = 0; r < 4; ++r) l_p[r] = rowsum16(l_p[r]);
  if (lr == 0) {
#pragma unroll
    for (int r = 0; r < 4; ++r) {
      mM[w][lg * 4 + r] = m_r[r];
      lL[w][lg * 4 + r] = l_p[r];
    }
  }
#pragma unroll
  for (int df = 0; df < 4; ++df)
#pragma unroll
    for (int r = 0; r < 4; ++r)
      oO[w][lg * 4 + r][df * 16 + lr] = accO[df][r];
  __syncthreads();

  // merge across waves: wave w handles d = w*16 + lr, rows lg*4+r
#pragma unroll
  for (int r = 0; r < 4; ++r) {
    int row = lg * 4 + r;
    float m0 = mM[0][row], m1 = mM[1][row], m2 = mM[2][row], m3 = mM[3][row];
    float ms = fmaxf(fmaxf(m0, m1), fmaxf(m2, m3));
    float a0 = EXP2(m0 - ms), a1 = EXP2(m1 - ms);
    float a2 = EXP2(m2 - ms), a3 = EXP2(m3 - ms);
    float ll = a0 * lL[0][row] + a1 * lL[1][row] + a2 * lL[2][row] + a3 * lL[3][row];
    int d = w * 16 + lr;
    float oo = a0 * oO[0][row][d] + a1 * oO[1][row][d] + a2 * oO[2][row][d] + a3 * oO[3][row][d];
    ao[(size_t)(qb + row) * DMODEL + hh * DHEAD + d] = __float2bfloat16(oo / ll);
  }
}

// ---------------------------------------------------------------------------
extern "C" void kernel_launch(void* const* d_in, const int* in_sizes, int n_in,
                              void* d_out, int out_size, void* d_ws, size_t ws_size,
                              hipStream_t stream) {
  const float* x = (const float*)d_in[0];
  const int* offs = (const int*)d_in[1];
  const float* fcos = (const float*)d_in[2];
  const float* fsin = (const float*)d_in[3];
  const float* ln0g = (const float*)d_in[4];
  const float* ln0b = (const float*)d_in[5];
  const float* ln1g = (const float*)d_in[6];
  const float* ln1b = (const float*)d_in[7];
  const float* wqkv = (const float*)d_in[8];
  const float* bqkv = (const float*)d_in[9];
  const float* wo = (const float*)d_in[10];
  const float* bo = (const float*)d_in[11];
  const float* wu = (const float*)d_in[12];
  const float* bu = (const float*)d_in[13];
  const float* wd = (const float*)d_in[14];
  const float* bd = (const float*)d_in[15];
  const float* lnfg = (const float*)d_in[16];
  const float* lnfb = (const float*)d_in[17];

  char* ws = (char*)d_ws;
  size_t off = 0;
  auto alloc = [&](size_t bytes) -> void* {
    void* p = ws + off;
    off += (bytes + 255) & ~(size_t)255;
    return p;
  };
  bf16* wqkvT = (bf16*)alloc((size_t)NLAYER * 3 * DMODEL * DMODEL * 2);
  bf16* woT = (bf16*)alloc((size_t)NLAYER * DMODEL * DMODEL * 2);
  bf16* wuT = (bf16*)alloc((size_t)NLAYER * DMODEL * FFDIM * 2);
  bf16* wdT = (bf16*)alloc((size_t)NLAYER * FFDIM * DMODEL * 2);
  float* hbuf = (float*)alloc((size_t)S_LEN * DMODEL * 4);
  bf16* ybuf = (bf16*)alloc((size_t)S_LEN * DMODEL * 2);
  bf16* qkv = (bf16*)alloc((size_t)S_LEN * 3 * DMODEL * 2);
  bf16* qrb = (bf16*)alloc((size_t)S_LEN * DMODEL * 2);
  bf16* krb = (bf16*)alloc((size_t)S_LEN * DMODEL * 2);
  bf16* vTb = (bf16*)alloc((size_t)S_LEN * DMODEL * 2);
  bf16* aob = (bf16*)alloc((size_t)S_LEN * DMODEL * 2);
  bf16* midb = (bf16*)alloc((size_t)S_LEN * FFDIM * 2);

  for (int ly = 0; ly < NLAYER; ++ly) {
    k_tcast<<<dim3(3 * DMODEL / 32, DMODEL / 32), 256, 0, stream>>>(
        wqkv + (size_t)ly * DMODEL * 3 * DMODEL, wqkvT + (size_t)ly * 3 * DMODEL * DMODEL, DMODEL, 3 * DMODEL);
    k_tcast<<<dim3(DMODEL / 32, DMODEL / 32), 256, 0, stream>>>(
        wo + (size_t)ly * DMODEL * DMODEL, woT + (size_t)ly * DMODEL * DMODEL, DMODEL, DMODEL);
    k_tcast<<<dim3(FFDIM / 32, DMODEL / 32), 256, 0, stream>>>(
        wu + (size_t)ly * DMODEL * FFDIM, wuT + (size_t)ly * DMODEL * FFDIM, DMODEL, FFDIM);
    k_tcast<<<dim3(DMODEL / 32, FFDIM / 32), 256, 0, stream>>>(
        wd + (size_t)ly * FFDIM * DMODEL, wdT + (size_t)ly * FFDIM * DMODEL, FFDIM, DMODEL);
  }
  hipMemcpyAsync(hbuf, x, (size_t)S_LEN * DMODEL * 4, hipMemcpyDeviceToDevice, stream);

  for (int ly = 0; ly < NLAYER; ++ly) {
    k_ln<bf16><<<S_LEN, 256, 0, stream>>>(hbuf, ln0g + ly * DMODEL, ln0b + ly * DMODEL, ybuf);
    k_gemm_bt<0, 128><<<dim3(S_LEN / 128, 3 * DMODEL / 128), 256, 0, stream>>>(
        ybuf, wqkvT + (size_t)ly * 3 * DMODEL * DMODEL, bqkv + ly * 3 * DMODEL, nullptr, qkv,
        S_LEN, 3 * DMODEL, DMODEL);
    k_rope<<<S_LEN * NHEAD * 32 / 256, 256, 0, stream>>>(qkv, fcos, fsin, qrb, krb);
    k_tv<<<dim3(S_LEN / 64, NHEAD), 256, 0, stream>>>(qkv, vTb);
    k_attn<<<dim3(NHEAD, S_LEN / 16), 256, 0, stream>>>(qrb, krb, vTb, offs, aob);
    k_gemm_bt<1, 64><<<dim3(S_LEN / 64, DMODEL / 128), 256, 0, stream>>>(
        aob, woT + (size_t)ly * DMODEL * DMODEL, bo + ly * DMODEL, hbuf, hbuf,
        S_LEN, DMODEL, DMODEL);
    k_ln<bf16><<<S_LEN, 256, 0, stream>>>(hbuf, ln1g + ly * DMODEL, ln1b + ly * DMODEL, ybuf);
    k_gemm_bt<2, 128><<<dim3(S_LEN / 128, FFDIM / 128), 256, 0, stream>>>(
        ybuf, wuT + (size_t)ly * DMODEL * FFDIM, bu + ly * FFDIM, nullptr, midb,
        S_LEN, FFDIM, DMODEL);
    k_gemm_bt<1, 64><<<dim3(S_LEN / 64, DMODEL / 128), 256, 0, stream>>>(
        midb, wdT + (size_t)ly * FFDIM * DMODEL, bd + ly * DMODEL, hbuf, hbuf,
        S_LEN, DMODEL, FFDIM);
  }
  k_ln<float><<<S_LEN, 256, 0, stream>>>(hbuf, lnfg, lnfb, (float*)d_out);
}

// Round 5
// 504.355 us; speedup vs baseline: 1.2697x; 1.2697x over previous
//
#include <hip/hip_runtime.h>
#include <hip/hip_bf16.h>
#include <stdint.h>
#include <math.h>

#define S_LEN 2048
#define DMODEL 1024
#define NHEAD 16
#define DHEAD 64
#define FFDIM 4096
#define NLAYER 2

using bf16 = __hip_bfloat16;
typedef __attribute__((ext_vector_type(8))) short bf16x8;
typedef __attribute__((ext_vector_type(4))) float f32x4;
typedef __attribute__((ext_vector_type(16))) float f32x16;
typedef __attribute__((ext_vector_type(4))) int i32x4;

#define MFMA16x16(A, B, C) __builtin_amdgcn_mfma_f32_16x16x32_bf16(A, B, C, 0, 0, 0)
#define MFMA32x32(A, B, C) __builtin_amdgcn_mfma_f32_32x32x16_bf16(A, B, C, 0, 0, 0)
#define EXP2(x) __builtin_amdgcn_exp2f(x)

__device__ __forceinline__ float bf2f(uint32_t u16bits) {
  union { uint32_t i; float f; } x;
  x.i = u16bits << 16;
  return x.f;
}
__device__ __forceinline__ uint16_t f2bf(float f) {
  return __builtin_bit_cast(uint16_t, __float2bfloat16(f));
}

// v_cvt_pk_bf16_f32: pack two f32 -> one dword of 2 bf16 (no builtin on gfx950)
__device__ __forceinline__ uint32_t cvtpk(float lo, float hi) {
  uint32_t r;
  asm("v_cvt_pk_bf16_f32 %0, %1, %2" : "=v"(r) : "v"(lo), "v"(hi));
  return r;
}
// v_permlane32_swap_b32: a' = [a.low32lanes, b.low32lanes], b' = [a.hi, b.hi]
__device__ __forceinline__ void pl32swap(uint32_t& a, uint32_t& b) {
#if __has_builtin(__builtin_amdgcn_permlane32_swap)
  typedef __attribute__((ext_vector_type(2))) int i32x2;
  i32x2 r = __builtin_amdgcn_permlane32_swap((int)a, (int)b, false, false);
  a = (uint32_t)r.x;
  b = (uint32_t)r.y;
#else
  asm volatile("v_permlane32_swap_b32 %0, %1" : "+v"(a), "+v"(b));
#endif
}

// ---------------------------------------------------------------------------
// Weight cast + transpose: in fp32 (R x C)  ->  out bf16 (C x R)
// ---------------------------------------------------------------------------
__global__ __launch_bounds__(256) void k_tcast(const float* __restrict__ in,
                                               bf16* __restrict__ out,
                                               int R, int C) {
  __shared__ float tl[32][33];
  int t = threadIdx.x;
  int r0 = blockIdx.y * 32, c0 = blockIdx.x * 32;
  int cl = t & 31, rl = t >> 5;
#pragma unroll
  for (int i = 0; i < 4; ++i)
    tl[rl + i * 8][cl] = in[(size_t)(r0 + rl + i * 8) * C + c0 + cl];
  __syncthreads();
#pragma unroll
  for (int i = 0; i < 4; ++i)
    out[(size_t)(c0 + rl + i * 8) * R + r0 + cl] = __float2bfloat16(tl[cl][rl + i * 8]);
}

// ---------------------------------------------------------------------------
// LayerNorm over DMODEL=1024
// ---------------------------------------------------------------------------
__device__ __forceinline__ void ln_store4(bf16* p, float a, float b, float c, float d) {
  uint2 u;
  u.x = (uint32_t)f2bf(a) | ((uint32_t)f2bf(b) << 16);
  u.y = (uint32_t)f2bf(c) | ((uint32_t)f2bf(d) << 16);
  *(uint2*)p = u;
}
__device__ __forceinline__ void ln_store4(float* p, float a, float b, float c, float d) {
  *(float4*)p = make_float4(a, b, c, d);
}

template <typename OUT>
__global__ __launch_bounds__(256) void k_ln(const float* __restrict__ h,
                                            const float* __restrict__ g,
                                            const float* __restrict__ b,
                                            OUT* __restrict__ y) {
  int row = blockIdx.x, t = threadIdx.x;
  const float4 v = ((const float4*)(h + (size_t)row * DMODEL))[t];
  float s = v.x + v.y + v.z + v.w;
  float s2 = v.x * v.x + v.y * v.y + v.z * v.z + v.w * v.w;
#pragma unroll
  for (int off = 32; off > 0; off >>= 1) {
    s += __shfl_down(s, off);
    s2 += __shfl_down(s2, off);
  }
  __shared__ float red[8];
  int w = t >> 6;
  if ((t & 63) == 0) { red[w] = s; red[4 + w] = s2; }
  __syncthreads();
  s = red[0] + red[1] + red[2] + red[3];
  s2 = red[4] + red[5] + red[6] + red[7];
  float mean = s * (1.0f / DMODEL);
  float var = s2 * (1.0f / DMODEL) - mean * mean;
  float rstd = rsqrtf(var + 1e-5f);
  float4 gv = ((const float4*)g)[t];
  float4 bv = ((const float4*)b)[t];
  float o0 = (v.x - mean) * rstd * gv.x + bv.x;
  float o1 = (v.y - mean) * rstd * gv.y + bv.y;
  float o2 = (v.z - mean) * rstd * gv.z + bv.z;
  float o3 = (v.w - mean) * rstd * gv.w + bv.w;
  ln_store4(y + (size_t)row * DMODEL + t * 4, o0, o1, o2, o3);
}

// ---------------------------------------------------------------------------
// RoPE on q,k sections of qkv
// ---------------------------------------------------------------------------
__global__ __launch_bounds__(256) void k_rope(const bf16* __restrict__ qkv,
                                              const float* __restrict__ fcos,
                                              const float* __restrict__ fsin,
                                              bf16* __restrict__ qr,
                                              bf16* __restrict__ kr) {
  int idx = blockIdx.x * 256 + threadIdx.x;
  int p = idx & 31;
  int hh = (idx >> 5) & (NHEAD - 1);
  int s = idx >> 9;
  float c = fcos[s * 32 + p], sn = fsin[s * 32 + p];
  int colq = hh * DHEAD + 2 * p;
  uint32_t rq = *(const uint32_t*)(qkv + (size_t)s * 3 * DMODEL + colq);
  uint32_t rk = *(const uint32_t*)(qkv + (size_t)s * 3 * DMODEL + DMODEL + colq);
  {
    float te = bf2f(rq & 0xffffu), to = bf2f(rq >> 16);
    uint32_t outv = (uint32_t)f2bf(te * c - to * sn) | ((uint32_t)f2bf(te * sn + to * c) << 16);
    *(uint32_t*)(qr + (size_t)s * DMODEL + colq) = outv;
  }
  {
    float te = bf2f(rk & 0xffffu), to = bf2f(rk >> 16);
    uint32_t outv = (uint32_t)f2bf(te * c - to * sn) | ((uint32_t)f2bf(te * sn + to * c) << 16);
    *(uint32_t*)(kr + (size_t)s * DMODEL + colq) = outv;
  }
}

// ---------------------------------------------------------------------------
// V transpose per head: vT[h][d][s]
// ---------------------------------------------------------------------------
__global__ __launch_bounds__(256) void k_tv(const bf16* __restrict__ qkv,
                                            bf16* __restrict__ vT) {
  __shared__ bf16 tl[64][65];
  int t = threadIdx.x;
  int hh = blockIdx.y;
  int sb = blockIdx.x * 64;
#pragma unroll
  for (int i = 0; i < 16; ++i) {
    int e = i * 256 + t;
    int sl = e >> 6, d = e & 63;
    tl[sl][d] = qkv[(size_t)(sb + sl) * 3 * DMODEL + 2 * DMODEL + hh * DHEAD + d];
  }
  __syncthreads();
#pragma unroll
  for (int i = 0; i < 16; ++i) {
    int e = i * 256 + t;
    int d = e >> 6, sl = e & 63;
    vT[(size_t)(hh * DHEAD + d) * S_LEN + sb + sl] = tl[sl][d];
  }
}

// ---------------------------------------------------------------------------
// GEMM: C[M,N] = A[M,K](bf16) * BT[N,K]^T + bias[N].
// EPI 0: bf16.  EPI 1: fp32 = res + acc + bias.  EPI 2: gelu -> bf16.
// ---------------------------------------------------------------------------
template <int EPI, int BM>
__global__ __launch_bounds__(256) void k_gemm_bt(const bf16* __restrict__ A,
                                                 const bf16* __restrict__ BT,
                                                 const float* __restrict__ bias,
                                                 const float* __restrict__ res,
                                                 void* __restrict__ out,
                                                 int M, int N, int K) {
  constexpr int MF = BM / 32;  // m-frags per wave
  __shared__ bf16 As[BM * 32];
  __shared__ bf16 Bs[128 * 32];
  int t = threadIdx.x;
  int w = t >> 6, l = t & 63, lr = l & 15, lg = l >> 4;
  int bm = blockIdx.x * BM, bn = blockIdx.y * 128;
  int wm = (w >> 1) * (BM / 2), wn = (w & 1) * 64;

  f32x4 zero4 = {0.f, 0.f, 0.f, 0.f};
  f32x4 acc[MF][4];
#pragma unroll
  for (int mf = 0; mf < MF; ++mf)
#pragma unroll
    for (int nf = 0; nf < 4; ++nf) acc[mf][nf] = zero4;

  for (int kt = 0; kt < K; kt += 32) {
    __syncthreads();
#pragma unroll
    for (int i = 0; i < BM / 64; ++i) {
      int chunk = i * 256 + t;
      int row = chunk >> 2, ko = (chunk & 3) * 8;
      __builtin_amdgcn_global_load_lds(
          (__attribute__((address_space(1))) void*)(A + (size_t)(bm + row) * K + kt + ko),
          (__attribute__((address_space(3))) void*)(As + chunk * 8), 16, 0, 0);
    }
#pragma unroll
    for (int i = 0; i < 2; ++i) {
      int chunk = i * 256 + t;
      int row = chunk >> 2, ko = (chunk & 3) * 8;
      __builtin_amdgcn_global_load_lds(
          (__attribute__((address_space(1))) void*)(BT + (size_t)(bn + row) * K + kt + ko),
          (__attribute__((address_space(3))) void*)(Bs + chunk * 8), 16, 0, 0);
    }
    __syncthreads();
    bf16x8 af[MF], bfr[4];
#pragma unroll
    for (int mf = 0; mf < MF; ++mf)
      af[mf] = *(const bf16x8*)(As + (wm + mf * 16 + lr) * 32 + lg * 8);
#pragma unroll
    for (int nf = 0; nf < 4; ++nf)
      bfr[nf] = *(const bf16x8*)(Bs + (wn + nf * 16 + lr) * 32 + lg * 8);
#pragma unroll
    for (int mf = 0; mf < MF; ++mf)
#pragma unroll
      for (int nf = 0; nf < 4; ++nf)
        acc[mf][nf] = MFMA16x16(af[mf], bfr[nf], acc[mf][nf]);
  }

  float* outf = (float*)out;
  bf16* outb = (bf16*)out;
#pragma unroll
  for (int mf = 0; mf < MF; ++mf) {
#pragma unroll
    for (int nf = 0; nf < 4; ++nf) {
      int col = bn + wn + nf * 16 + lr;
      float bv = bias[col];
      int row0 = bm + wm + mf * 16 + lg * 4;
#pragma unroll
      for (int r = 0; r < 4; ++r) {
        float v = acc[mf][nf][r] + bv;
        size_t idx = (size_t)(row0 + r) * N + col;
        if (EPI == 0) {
          outb[idx] = __float2bfloat16(v);
        } else if (EPI == 1) {
          outf[idx] = res[idx] + v;
        } else {
          float gl = 0.5f * v * (1.0f + tanhf(0.7978845608028654f * (v + 0.044715f * v * v * v)));
          outb[idx] = __float2bfloat16(gl);
        }
      }
    }
  }
}

// ---------------------------------------------------------------------------
// Flash attention v4: swapped-operand 32x32x16 MFMA, fully in-register softmax.
//
// Per wave: 32 queries (col = lane&31) x 512 keys (16 tiles of 32, split-K
// across 4 waves). S^T = mfma(A=K, B=Q): each lane holds 16 of 32 key-scores
// for ONE query -> row stats are 15 in-reg fmax + one v_permlane32_swap.
// P^T built in-register via v_cvt_pk_bf16_f32 + permlane32_swap (T12); PV is
// O^T = mfma(A=V^T, B=P^T). No LDS in the main loop; merge partials at end.
// Segment bias: same-seg(key,q) <=> key in [lo,hi) -> per-reg range test.
// ---------------------------------------------------------------------------
__global__ __launch_bounds__(256, 4) void k_attn(const bf16* __restrict__ qr,
                                                 const bf16* __restrict__ kr,
                                                 const bf16* __restrict__ vT,
                                                 const int* __restrict__ offs,
                                                 bf16* __restrict__ ao) {
  __shared__ float oO[4][64][33];
  __shared__ float mM[4][32];
  __shared__ float lL[4][32];

  int t = threadIdx.x, w = t >> 6, l = t & 63;
  int ql = l & 31, hi = l >> 5, hi8 = hi * 8;
  int hh = blockIdx.x, qb = blockIdx.y * 32;
  int h64 = hh * DHEAD;

  constexpr float LOG2E = 1.4426950408889634f;
  constexpr float C1 = 0.125f * LOG2E;

  // segment range [sl0, sh0) containing this lane's query
  int q = qb + ql;
  int o0 = offs[0], o1 = offs[1], o2 = offs[2], o3 = offs[3], o4 = offs[4];
  int sl0 = -1073741824, sh0 = 1073741824;
  sl0 = (o0 <= q) ? o0 : sl0;
  sl0 = (o1 <= q) ? o1 : sl0;
  sl0 = (o2 <= q) ? o2 : sl0;
  sl0 = (o3 <= q) ? o3 : sl0;
  sl0 = (o4 <= q) ? o4 : sl0;
  sh0 = (o4 > q) ? o4 : sh0;
  sh0 = (o3 > q) ? o3 : sh0;
  sh0 = (o2 > q) ? o2 : sh0;
  sh0 = (o1 > q) ? o1 : sh0;
  sh0 = (o0 > q) ? o0 : sh0;
  uint32_t spanu = (uint32_t)(sh0 - sl0);

  // Q fragments (B-operand), hoisted: Q[qb+ql][d0 + 8*hi + j], d0 = 0,16,32,48
  const bf16* qbase = qr + (size_t)q * DMODEL + h64 + hi8;
  bf16x8 qf0 = *(const bf16x8*)(qbase);
  bf16x8 qf1 = *(const bf16x8*)(qbase + 16);
  bf16x8 qf2 = *(const bf16x8*)(qbase + 32);
  bf16x8 qf3 = *(const bf16x8*)(qbase + 48);

  f32x16 oC0, oC1;
#pragma unroll
  for (int r = 0; r < 16; ++r) { oC0[r] = 0.f; oC1[r] = 0.f; }
  float m_r = -1e30f, l_r = 0.f;

  const bf16* vrow = vT + (size_t)(h64 + ql) * S_LEN + hi8;

  for (int it = 0; it < 16; ++it) {
    int j0 = w * 512 + it * 32;
    // ---- K fragments (A-operand): K[j0+ql][d0 + 8*hi + j] ----
    const bf16* kbase = kr + (size_t)(j0 + ql) * DMODEL + h64 + hi8;
    bf16x8 kf0 = *(const bf16x8*)(kbase);
    bf16x8 kf1 = *(const bf16x8*)(kbase + 16);
    bf16x8 kf2 = *(const bf16x8*)(kbase + 32);
    bf16x8 kf3 = *(const bf16x8*)(kbase + 48);
    f32x16 sC;
#pragma unroll
    for (int r = 0; r < 16; ++r) sC[r] = 0.f;
    __builtin_amdgcn_s_setprio(1);
    sC = MFMA32x32(kf0, qf0, sC);
    sC = MFMA32x32(kf1, qf1, sC);
    sC = MFMA32x32(kf2, qf2, sC);
    sC = MFMA32x32(kf3, qf3, sC);
    __builtin_amdgcn_s_setprio(0);

    // ---- scale + segment bias: key(r) = j0 + 4*hi + (r&3) + 8*(r>>2) ----
    int tt = j0 + hi * 4 - sl0;
#pragma unroll
    for (int r = 0; r < 16; ++r) {
      int ku = tt + ((r & 3) + 8 * (r >> 2));
      float bias = ((uint32_t)ku < spanu) ? LOG2E : 0.0f;
      sC[r] = sC[r] * C1 + bias;
    }
    // ---- row max over 32 keys: 15 in-reg fmax + one permlane swap ----
    float rm = sC[0];
#pragma unroll
    for (int r = 1; r < 16; ++r) rm = fmaxf(rm, sC[r]);
    uint32_t ra = __builtin_bit_cast(uint32_t, rm), rb = ra;
    pl32swap(ra, rb);
    float rmax = fmaxf(__builtin_bit_cast(float, ra), __builtin_bit_cast(float, rb));

    // ---- defer-max (T13): rescale only when max grows by > 8 (log2) ----
    if (__any(rmax > m_r + 8.0f)) {
      float mn = fmaxf(m_r, rmax);
      float fs = EXP2(m_r - mn);
      m_r = mn;
      l_r *= fs;
#pragma unroll
      for (int r = 0; r < 16; ++r) { oC0[r] *= fs; oC1[r] *= fs; }
    }
    // ---- P = exp2(s - m), accumulate per-lane l ----
#pragma unroll
    for (int r = 0; r < 16; ++r) {
      float pv = EXP2(sC[r] - m_r);
      sC[r] = pv;
      l_r += pv;
    }
    // ---- P^T B-operand: cvt_pk pairs + permlane32 swaps ----
    uint32_t u0 = cvtpk(sC[0], sC[1]), u1 = cvtpk(sC[2], sC[3]);
    uint32_t u2 = cvtpk(sC[4], sC[5]), u3 = cvtpk(sC[6], sC[7]);
    uint32_t u4 = cvtpk(sC[8], sC[9]), u5 = cvtpk(sC[10], sC[11]);
    uint32_t u6 = cvtpk(sC[12], sC[13]), u7 = cvtpk(sC[14], sC[15]);
    pl32swap(u0, u2);
    pl32swap(u1, u3);
    pl32swap(u4, u6);
    pl32swap(u5, u7);
    i32x4 pi0 = {(int)u0, (int)u1, (int)u2, (int)u3};
    i32x4 pi1 = {(int)u4, (int)u5, (int)u6, (int)u7};
    bf16x8 pb0 = __builtin_bit_cast(bf16x8, pi0);
    bf16x8 pb1 = __builtin_bit_cast(bf16x8, pi1);

    // ---- V fragments (A-operand): vT[h64 + dt*32 + ql][j0 + kk*16 + 8hi + j] ----
    const bf16* vbase = vrow + j0;
    bf16x8 va00 = *(const bf16x8*)(vbase);
    bf16x8 va01 = *(const bf16x8*)(vbase + 16);
    bf16x8 va10 = *(const bf16x8*)(vbase + 32 * S_LEN);
    bf16x8 va11 = *(const bf16x8*)(vbase + 32 * S_LEN + 16);
    __builtin_amdgcn_s_setprio(1);
    oC0 = MFMA32x32(va00, pb0, oC0);
    oC0 = MFMA32x32(va01, pb1, oC0);
    oC1 = MFMA32x32(va10, pb0, oC1);
    oC1 = MFMA32x32(va11, pb1, oC1);
    __builtin_amdgcn_s_setprio(0);
  }

  // ---- combine l across the hi pair, publish partials ----
  {
    uint32_t la = __builtin_bit_cast(uint32_t, l_r), lb = la;
    pl32swap(la, lb);
    l_r = __builtin_bit_cast(float, la) + __builtin_bit_cast(float, lb);
  }
  if (hi == 0) {
    mM[w][ql] = m_r;
    lL[w][ql] = l_r;
  }
#pragma unroll
  for (int r = 0; r < 16; ++r) {
    int d = (r & 3) + 8 * (r >> 2) + 4 * hi;
    oO[w][d][ql] = oC0[r];
    oO[w][d + 32][ql] = oC1[r];
  }
  __syncthreads();

  // ---- merge 4 wave-partials: thread -> (q = t&31, d = (t>>5)*8 .. +7) ----
  {
    int mq = t & 31, dbse = (t >> 5) * 8;
    float m0 = mM[0][mq], m1 = mM[1][mq], m2 = mM[2][mq], m3 = mM[3][mq];
    float ms = fmaxf(fmaxf(m0, m1), fmaxf(m2, m3));
    float a0 = EXP2(m0 - ms), a1 = EXP2(m1 - ms), a2 = EXP2(m2 - ms), a3 = EXP2(m3 - ms);
    float ll = a0 * lL[0][mq] + a1 * lL[1][mq] + a2 * lL[2][mq] + a3 * lL[3][mq];
    float inv = 1.0f / ll;
    uint4 pkv;
    uint32_t pw[4];
#pragma unroll
    for (int i = 0; i < 4; ++i) {
      int d0 = dbse + 2 * i, d1 = dbse + 2 * i + 1;
      float e0 = (a0 * oO[0][d0][mq] + a1 * oO[1][d0][mq] + a2 * oO[2][d0][mq] +
                  a3 * oO[3][d0][mq]) * inv;
      float e1 = (a0 * oO[0][d1][mq] + a1 * oO[1][d1][mq] + a2 * oO[2][d1][mq] +
                  a3 * oO[3][d1][mq]) * inv;
      pw[i] = (uint32_t)f2bf(e0) | ((uint32_t)f2bf(e1) << 16);
    }
    pkv.x = pw[0]; pkv.y = pw[1]; pkv.z = pw[2]; pkv.w = pw[3];
    *(uint4*)(ao + (size_t)(qb + mq) * DMODEL + h64 + dbse) = pkv;
  }
}

// ---------------------------------------------------------------------------
extern "C" void kernel_launch(void* const* d_in, const int* in_sizes, int n_in,
                              void* d_out, int out_size, void* d_ws, size_t ws_size,
                              hipStream_t stream) {
  const float* x = (const float*)d_in[0];
  const int* offs = (const int*)d_in[1];
  const float* fcos = (const float*)d_in[2];
  const float* fsin = (const float*)d_in[3];
  const float* ln0g = (const float*)d_in[4];
  const float* ln0b = (const float*)d_in[5];
  const float* ln1g = (const float*)d_in[6];
  const float* ln1b = (const float*)d_in[7];
  const float* wqkv = (const float*)d_in[8];
  const float* bqkv = (const float*)d_in[9];
  const float* wo = (const float*)d_in[10];
  const float* bo = (const float*)d_in[11];
  const float* wu = (const float*)d_in[12];
  const float* bu = (const float*)d_in[13];
  const float* wd = (const float*)d_in[14];
  const float* bd = (const float*)d_in[15];
  const float* lnfg = (const float*)d_in[16];
  const float* lnfb = (const float*)d_in[17];

  char* ws = (char*)d_ws;
  size_t off = 0;
  auto alloc = [&](size_t bytes) -> void* {
    void* p = ws + off;
    off += (bytes + 255) & ~(size_t)255;
    return p;
  };
  bf16* wqkvT = (bf16*)alloc((size_t)NLAYER * 3 * DMODEL * DMODEL * 2);
  bf16* woT = (bf16*)alloc((size_t)NLAYER * DMODEL * DMODEL * 2);
  bf16* wuT = (bf16*)alloc((size_t)NLAYER * DMODEL * FFDIM * 2);
  bf16* wdT = (bf16*)alloc((size_t)NLAYER * FFDIM * DMODEL * 2);
  float* hbuf = (float*)alloc((size_t)S_LEN * DMODEL * 4);
  bf16* ybuf = (bf16*)alloc((size_t)S_LEN * DMODEL * 2);
  bf16* qkv = (bf16*)alloc((size_t)S_LEN * 3 * DMODEL * 2);
  bf16* qrb = (bf16*)alloc((size_t)S_LEN * DMODEL * 2);
  bf16* krb = (bf16*)alloc((size_t)S_LEN * DMODEL * 2);
  bf16* vTb = (bf16*)alloc((size_t)S_LEN * DMODEL * 2);
  bf16* aob = (bf16*)alloc((size_t)S_LEN * DMODEL * 2);
  bf16* midb = (bf16*)alloc((size_t)S_LEN * FFDIM * 2);

  for (int ly = 0; ly < NLAYER; ++ly) {
    k_tcast<<<dim3(3 * DMODEL / 32, DMODEL / 32), 256, 0, stream>>>(
        wqkv + (size_t)ly * DMODEL * 3 * DMODEL, wqkvT + (size_t)ly * 3 * DMODEL * DMODEL, DMODEL, 3 * DMODEL);
    k_tcast<<<dim3(DMODEL / 32, DMODEL / 32), 256, 0, stream>>>(
        wo + (size_t)ly * DMODEL * DMODEL, woT + (size_t)ly * DMODEL * DMODEL, DMODEL, DMODEL);
    k_tcast<<<dim3(FFDIM / 32, DMODEL / 32), 256, 0, stream>>>(
        wu + (size_t)ly * DMODEL * FFDIM, wuT + (size_t)ly * DMODEL * FFDIM, DMODEL, FFDIM);
    k_tcast<<<dim3(DMODEL / 32, FFDIM / 32), 256, 0, stream>>>(
        wd + (size_t)ly * FFDIM * DMODEL, wdT + (size_t)ly * FFDIM * DMODEL, FFDIM, DMODEL);
  }
  hipMemcpyAsync(hbuf, x, (size_t)S_LEN * DMODEL * 4, hipMemcpyDeviceToDevice, stream);

  for (int ly = 0; ly < NLAYER; ++ly) {
    k_ln<bf16><<<S_LEN, 256, 0, stream>>>(hbuf, ln0g + ly * DMODEL, ln0b + ly * DMODEL, ybuf);
    k_gemm_bt<0, 128><<<dim3(S_LEN / 128, 3 * DMODEL / 128), 256, 0, stream>>>(
        ybuf, wqkvT + (size_t)ly * 3 * DMODEL * DMODEL, bqkv + ly * 3 * DMODEL, nullptr, qkv,
        S_LEN, 3 * DMODEL, DMODEL);
    k_rope<<<S_LEN * NHEAD * 32 / 256, 256, 0, stream>>>(qkv, fcos, fsin, qrb, krb);
    k_tv<<<dim3(S_LEN / 64, NHEAD), 256, 0, stream>>>(qkv, vTb);
    k_attn<<<dim3(NHEAD, S_LEN / 32), 256, 0, stream>>>(qrb, krb, vTb, offs, aob);
    k_gemm_bt<1, 64><<<dim3(S_LEN / 64, DMODEL / 128), 256, 0, stream>>>(
        aob, woT + (size_t)ly * DMODEL * DMODEL, bo + ly * DMODEL, hbuf, hbuf,
        S_LEN, DMODEL, DMODEL);
    k_ln<bf16><<<S_LEN, 256, 0, stream>>>(hbuf, ln1g + ly * DMODEL, ln1b + ly * DMODEL, ybuf);
    k_gemm_bt<2, 128><<<dim3(S_LEN / 128, FFDIM / 128), 256, 0, stream>>>(
        ybuf, wuT + (size_t)ly * DMODEL * FFDIM, bu + ly * FFDIM, nullptr, midb,
        S_LEN, FFDIM, DMODEL);
    k_gemm_bt<1, 64><<<dim3(S_LEN / 64, DMODEL / 128), 256, 0, stream>>>(
        midb, wdT + (size_t)ly * FFDIM * DMODEL, bd + ly * DMODEL, hbuf, hbuf,
        S_LEN, DMODEL, FFDIM);
  }
  k_ln<float><<<S_LEN, 256, 0, stream>>>(hbuf, lnfg, lnfb, (float*)d_out);
}

// Round 6
// 420.448 us; speedup vs baseline: 1.5230x; 1.1996x over previous
//
#include <hip/hip_runtime.h>
#include <hip/hip_bf16.h>
#include <stdint.h>
#include <math.h>

#define S_LEN 2048
#define DMODEL 1024
#define NHEAD 16
#define DHEAD 64
#define FFDIM 4096
#define NLAYER 2

using bf16 = __hip_bfloat16;
typedef __attribute__((ext_vector_type(8))) short bf16x8;
typedef __attribute__((ext_vector_type(4))) float f32x4;
typedef __attribute__((ext_vector_type(16))) float f32x16;
typedef __attribute__((ext_vector_type(4))) int i32x4;

#define MFMA16x16(A, B, C) __builtin_amdgcn_mfma_f32_16x16x32_bf16(A, B, C, 0, 0, 0)
#define MFMA32x32(A, B, C) __builtin_amdgcn_mfma_f32_32x32x16_bf16(A, B, C, 0, 0, 0)
#define EXP2(x) __builtin_amdgcn_exp2f(x)

__device__ __forceinline__ float bf2f(uint32_t u16bits) {
  union { uint32_t i; float f; } x;
  x.i = u16bits << 16;
  return x.f;
}
__device__ __forceinline__ uint16_t f2bf(float f) {
  return __builtin_bit_cast(uint16_t, __float2bfloat16(f));
}

// v_cvt_pk_bf16_f32: pack two f32 -> one dword of 2 bf16 (no builtin on gfx950)
__device__ __forceinline__ uint32_t cvtpk(float lo, float hi) {
  uint32_t r;
  asm("v_cvt_pk_bf16_f32 %0, %1, %2" : "=v"(r) : "v"(lo), "v"(hi));
  return r;
}
// v_permlane32_swap_b32
__device__ __forceinline__ void pl32swap(uint32_t& a, uint32_t& b) {
#if __has_builtin(__builtin_amdgcn_permlane32_swap)
  typedef __attribute__((ext_vector_type(2))) int i32x2;
  i32x2 r = __builtin_amdgcn_permlane32_swap((int)a, (int)b, false, false);
  a = (uint32_t)r.x;
  b = (uint32_t)r.y;
#else
  asm volatile("v_permlane32_swap_b32 %0, %1" : "+v"(a), "+v"(b));
#endif
}

// ---------------------------------------------------------------------------
// Weight cast + transpose: in fp32 (R x C)  ->  out bf16 (C x R)
// ---------------------------------------------------------------------------
__global__ __launch_bounds__(256) void k_tcast(const float* __restrict__ in,
                                               bf16* __restrict__ out,
                                               int R, int C) {
  __shared__ float tl[32][33];
  int t = threadIdx.x;
  int r0 = blockIdx.y * 32, c0 = blockIdx.x * 32;
  int cl = t & 31, rl = t >> 5;
#pragma unroll
  for (int i = 0; i < 4; ++i)
    tl[rl + i * 8][cl] = in[(size_t)(r0 + rl + i * 8) * C + c0 + cl];
  __syncthreads();
#pragma unroll
  for (int i = 0; i < 4; ++i)
    out[(size_t)(c0 + rl + i * 8) * R + r0 + cl] = __float2bfloat16(tl[cl][rl + i * 8]);
}

// ---------------------------------------------------------------------------
// LayerNorm over DMODEL=1024
// ---------------------------------------------------------------------------
__device__ __forceinline__ void ln_store4(bf16* p, float a, float b, float c, float d) {
  uint2 u;
  u.x = (uint32_t)f2bf(a) | ((uint32_t)f2bf(b) << 16);
  u.y = (uint32_t)f2bf(c) | ((uint32_t)f2bf(d) << 16);
  *(uint2*)p = u;
}
__device__ __forceinline__ void ln_store4(float* p, float a, float b, float c, float d) {
  *(float4*)p = make_float4(a, b, c, d);
}

template <typename OUT>
__global__ __launch_bounds__(256) void k_ln(const float* __restrict__ h,
                                            const float* __restrict__ g,
                                            const float* __restrict__ b,
                                            OUT* __restrict__ y) {
  int row = blockIdx.x, t = threadIdx.x;
  const float4 v = ((const float4*)(h + (size_t)row * DMODEL))[t];
  float s = v.x + v.y + v.z + v.w;
  float s2 = v.x * v.x + v.y * v.y + v.z * v.z + v.w * v.w;
#pragma unroll
  for (int off = 32; off > 0; off >>= 1) {
    s += __shfl_down(s, off);
    s2 += __shfl_down(s2, off);
  }
  __shared__ float red[8];
  int w = t >> 6;
  if ((t & 63) == 0) { red[w] = s; red[4 + w] = s2; }
  __syncthreads();
  s = red[0] + red[1] + red[2] + red[3];
  s2 = red[4] + red[5] + red[6] + red[7];
  float mean = s * (1.0f / DMODEL);
  float var = s2 * (1.0f / DMODEL) - mean * mean;
  float rstd = rsqrtf(var + 1e-5f);
  float4 gv = ((const float4*)g)[t];
  float4 bv = ((const float4*)b)[t];
  float o0 = (v.x - mean) * rstd * gv.x + bv.x;
  float o1 = (v.y - mean) * rstd * gv.y + bv.y;
  float o2 = (v.z - mean) * rstd * gv.z + bv.z;
  float o3 = (v.w - mean) * rstd * gv.w + bv.w;
  ln_store4(y + (size_t)row * DMODEL + t * 4, o0, o1, o2, o3);
}

// ---------------------------------------------------------------------------
// RoPE on q,k sections of qkv
// ---------------------------------------------------------------------------
__global__ __launch_bounds__(256) void k_rope(const bf16* __restrict__ qkv,
                                              const float* __restrict__ fcos,
                                              const float* __restrict__ fsin,
                                              bf16* __restrict__ qr,
                                              bf16* __restrict__ kr) {
  int idx = blockIdx.x * 256 + threadIdx.x;
  int p = idx & 31;
  int hh = (idx >> 5) & (NHEAD - 1);
  int s = idx >> 9;
  float c = fcos[s * 32 + p], sn = fsin[s * 32 + p];
  int colq = hh * DHEAD + 2 * p;
  uint32_t rq = *(const uint32_t*)(qkv + (size_t)s * 3 * DMODEL + colq);
  uint32_t rk = *(const uint32_t*)(qkv + (size_t)s * 3 * DMODEL + DMODEL + colq);
  {
    float te = bf2f(rq & 0xffffu), to = bf2f(rq >> 16);
    uint32_t outv = (uint32_t)f2bf(te * c - to * sn) | ((uint32_t)f2bf(te * sn + to * c) << 16);
    *(uint32_t*)(qr + (size_t)s * DMODEL + colq) = outv;
  }
  {
    float te = bf2f(rk & 0xffffu), to = bf2f(rk >> 16);
    uint32_t outv = (uint32_t)f2bf(te * c - to * sn) | ((uint32_t)f2bf(te * sn + to * c) << 16);
    *(uint32_t*)(kr + (size_t)s * DMODEL + colq) = outv;
  }
}

// ---------------------------------------------------------------------------
// V transpose per head: vT[h][d][s]
// ---------------------------------------------------------------------------
__global__ __launch_bounds__(256) void k_tv(const bf16* __restrict__ qkv,
                                            bf16* __restrict__ vT) {
  __shared__ bf16 tl[64][65];
  int t = threadIdx.x;
  int hh = blockIdx.y;
  int sb = blockIdx.x * 64;
#pragma unroll
  for (int i = 0; i < 16; ++i) {
    int e = i * 256 + t;
    int sl = e >> 6, d = e & 63;
    tl[sl][d] = qkv[(size_t)(sb + sl) * 3 * DMODEL + 2 * DMODEL + hh * DHEAD + d];
  }
  __syncthreads();
#pragma unroll
  for (int i = 0; i < 16; ++i) {
    int e = i * 256 + t;
    int d = e >> 6, sl = e & 63;
    vT[(size_t)(hh * DHEAD + d) * S_LEN + sb + sl] = tl[sl][d];
  }
}

// ---------------------------------------------------------------------------
// GEMM v2: C[M,N] = A[M,K](bf16) * BT[N,K]^T, BK=64, XOR-swizzled LDS (T2),
// optional split-K via blockIdx.z (chunk [z*Kc, (z+1)*Kc)).
// EPI 0: bias -> bf16.  EPI 2: gelu(bias) -> bf16.  EPI 3: raw fp32 partial
// to out + z*M*N (bias/res applied later by k_reduce).
// Swizzle: physical 16B-slot = logical slot ^ (row&7). global_load_lds writes
// linearly, so the global SOURCE column is pre-swizzled (rule 21 / m173) and
// ds_read applies the same XOR -> every 8-lane b128 group covers 32 banks.
// ---------------------------------------------------------------------------
template <int EPI, int BM>
__global__ __launch_bounds__(256) void k_gemm2(const bf16* __restrict__ A,
                                               const bf16* __restrict__ BT,
                                               const float* __restrict__ bias,
                                               void* __restrict__ out,
                                               int M, int N, int K, int Kc) {
  constexpr int MF = BM / 32;  // m-frags per wave
  __shared__ bf16 As[BM * 64];
  __shared__ bf16 Bs[128 * 64];
  int t = threadIdx.x;
  int w = t >> 6, l = t & 63, lr = l & 15, lg = l >> 4;
  int bm = blockIdx.x * BM, bn = blockIdx.y * 128;
  int k0 = blockIdx.z * Kc;
  int wm = (w >> 1) * (BM / 2), wn = (w & 1) * 64;

  f32x4 zero4 = {0.f, 0.f, 0.f, 0.f};
  f32x4 acc[MF][4];
#pragma unroll
  for (int mf = 0; mf < MF; ++mf)
#pragma unroll
    for (int nf = 0; nf < 4; ++nf) acc[mf][nf] = zero4;

  for (int kt = 0; kt < Kc; kt += 64) {
    __syncthreads();
#pragma unroll
    for (int i = 0; i < BM / 32; ++i) {
      int chunk = i * 256 + t;
      int row = chunk >> 3;
      int scol = ((chunk ^ row) & 7) << 3;  // (slot ^ (row&7)) * 8
      __builtin_amdgcn_global_load_lds(
          (__attribute__((address_space(1))) void*)(A + (size_t)(bm + row) * K + k0 + kt + scol),
          (__attribute__((address_space(3))) void*)(As + chunk * 8), 16, 0, 0);
    }
#pragma unroll
    for (int i = 0; i < 4; ++i) {
      int chunk = i * 256 + t;
      int row = chunk >> 3;
      int scol = ((chunk ^ row) & 7) << 3;
      __builtin_amdgcn_global_load_lds(
          (__attribute__((address_space(1))) void*)(BT + (size_t)(bn + row) * K + k0 + kt + scol),
          (__attribute__((address_space(3))) void*)(Bs + chunk * 8), 16, 0, 0);
    }
    __syncthreads();
    bf16x8 af[2][MF], bfr[2][4];
#pragma unroll
    for (int h = 0; h < 2; ++h) {
#pragma unroll
      for (int mf = 0; mf < MF; ++mf) {
        int row = wm + mf * 16 + lr;
        af[h][mf] = *(const bf16x8*)(As + row * 64 + ((((h << 2) + lg) ^ (row & 7)) << 3));
      }
#pragma unroll
      for (int nf = 0; nf < 4; ++nf) {
        int row = wn + nf * 16 + lr;
        bfr[h][nf] = *(const bf16x8*)(Bs + row * 64 + ((((h << 2) + lg) ^ (row & 7)) << 3));
      }
    }
#pragma unroll
    for (int h = 0; h < 2; ++h)
#pragma unroll
      for (int mf = 0; mf < MF; ++mf)
#pragma unroll
        for (int nf = 0; nf < 4; ++nf)
          acc[mf][nf] = MFMA16x16(af[h][mf], bfr[h][nf], acc[mf][nf]);
  }

  if (EPI == 3) {
    float* outf = (float*)out + (size_t)blockIdx.z * ((size_t)M * N);
#pragma unroll
    for (int mf = 0; mf < MF; ++mf)
#pragma unroll
      for (int nf = 0; nf < 4; ++nf) {
        int col = bn + wn + nf * 16 + lr;
        int row0 = bm + wm + mf * 16 + lg * 4;
#pragma unroll
        for (int r = 0; r < 4; ++r)
          outf[(size_t)(row0 + r) * N + col] = acc[mf][nf][r];
      }
  } else {
    bf16* outb = (bf16*)out;
#pragma unroll
    for (int mf = 0; mf < MF; ++mf)
#pragma unroll
      for (int nf = 0; nf < 4; ++nf) {
        int col = bn + wn + nf * 16 + lr;
        float bv = bias[col];
        int row0 = bm + wm + mf * 16 + lg * 4;
#pragma unroll
        for (int r = 0; r < 4; ++r) {
          float v = acc[mf][nf][r] + bv;
          if (EPI == 2)
            v = 0.5f * v * (1.0f + tanhf(0.7978845608028654f * (v + 0.044715f * v * v * v)));
          outb[(size_t)(row0 + r) * N + col] = __float2bfloat16(v);
        }
      }
  }
}

// ---------------------------------------------------------------------------
// Split-K merge: hb = hb + bias + sum_ks part[ks]  (fp32, vectorized x4)
// ---------------------------------------------------------------------------
template <int KS>
__global__ __launch_bounds__(256) void k_reduce(const float* __restrict__ part,
                                                const float* __restrict__ bias,
                                                float* __restrict__ hb,
                                                int MN, int N) {
  int i4 = (blockIdx.x * 256 + threadIdx.x) * 4;
  float4 r = *(const float4*)(hb + i4);
  float4 b = *(const float4*)(bias + (i4 & (N - 1)));
  float sx = r.x + b.x, sy = r.y + b.y, sz = r.z + b.z, sw = r.w + b.w;
#pragma unroll
  for (int ks = 0; ks < KS; ++ks) {
    float4 p = *(const float4*)(part + (size_t)ks * MN + i4);
    sx += p.x; sy += p.y; sz += p.z; sw += p.w;
  }
  *(float4*)(hb + i4) = make_float4(sx, sy, sz, sw);
}

// ---------------------------------------------------------------------------
// Flash attention v4: swapped-operand 32x32x16 MFMA, in-register softmax.
// (unchanged from round 4)
// ---------------------------------------------------------------------------
__global__ __launch_bounds__(256, 4) void k_attn(const bf16* __restrict__ qr,
                                                 const bf16* __restrict__ kr,
                                                 const bf16* __restrict__ vT,
                                                 const int* __restrict__ offs,
                                                 bf16* __restrict__ ao) {
  __shared__ float oO[4][64][33];
  __shared__ float mM[4][32];
  __shared__ float lL[4][32];

  int t = threadIdx.x, w = t >> 6, l = t & 63;
  int ql = l & 31, hi = l >> 5, hi8 = hi * 8;
  int hh = blockIdx.x, qb = blockIdx.y * 32;
  int h64 = hh * DHEAD;

  constexpr float LOG2E = 1.4426950408889634f;
  constexpr float C1 = 0.125f * LOG2E;

  int q = qb + ql;
  int o0 = offs[0], o1 = offs[1], o2 = offs[2], o3 = offs[3], o4 = offs[4];
  int sl0 = -1073741824, sh0 = 1073741824;
  sl0 = (o0 <= q) ? o0 : sl0;
  sl0 = (o1 <= q) ? o1 : sl0;
  sl0 = (o2 <= q) ? o2 : sl0;
  sl0 = (o3 <= q) ? o3 : sl0;
  sl0 = (o4 <= q) ? o4 : sl0;
  sh0 = (o4 > q) ? o4 : sh0;
  sh0 = (o3 > q) ? o3 : sh0;
  sh0 = (o2 > q) ? o2 : sh0;
  sh0 = (o1 > q) ? o1 : sh0;
  sh0 = (o0 > q) ? o0 : sh0;
  uint32_t spanu = (uint32_t)(sh0 - sl0);

  const bf16* qbase = qr + (size_t)q * DMODEL + h64 + hi8;
  bf16x8 qf0 = *(const bf16x8*)(qbase);
  bf16x8 qf1 = *(const bf16x8*)(qbase + 16);
  bf16x8 qf2 = *(const bf16x8*)(qbase + 32);
  bf16x8 qf3 = *(const bf16x8*)(qbase + 48);

  f32x16 oC0, oC1;
#pragma unroll
  for (int r = 0; r < 16; ++r) { oC0[r] = 0.f; oC1[r] = 0.f; }
  float m_r = -1e30f, l_r = 0.f;

  const bf16* vrow = vT + (size_t)(h64 + ql) * S_LEN + hi8;

  for (int it = 0; it < 16; ++it) {
    int j0 = w * 512 + it * 32;
    const bf16* kbase = kr + (size_t)(j0 + ql) * DMODEL + h64 + hi8;
    bf16x8 kf0 = *(const bf16x8*)(kbase);
    bf16x8 kf1 = *(const bf16x8*)(kbase + 16);
    bf16x8 kf2 = *(const bf16x8*)(kbase + 32);
    bf16x8 kf3 = *(const bf16x8*)(kbase + 48);
    f32x16 sC;
#pragma unroll
    for (int r = 0; r < 16; ++r) sC[r] = 0.f;
    __builtin_amdgcn_s_setprio(1);
    sC = MFMA32x32(kf0, qf0, sC);
    sC = MFMA32x32(kf1, qf1, sC);
    sC = MFMA32x32(kf2, qf2, sC);
    sC = MFMA32x32(kf3, qf3, sC);
    __builtin_amdgcn_s_setprio(0);

    int tt = j0 + hi * 4 - sl0;
#pragma unroll
    for (int r = 0; r < 16; ++r) {
      int ku = tt + ((r & 3) + 8 * (r >> 2));
      float bias = ((uint32_t)ku < spanu) ? LOG2E : 0.0f;
      sC[r] = sC[r] * C1 + bias;
    }
    float rm = sC[0];
#pragma unroll
    for (int r = 1; r < 16; ++r) rm = fmaxf(rm, sC[r]);
    uint32_t ra = __builtin_bit_cast(uint32_t, rm), rb = ra;
    pl32swap(ra, rb);
    float rmax = fmaxf(__builtin_bit_cast(float, ra), __builtin_bit_cast(float, rb));

    if (__any(rmax > m_r + 8.0f)) {
      float mn = fmaxf(m_r, rmax);
      float fs = EXP2(m_r - mn);
      m_r = mn;
      l_r *= fs;
#pragma unroll
      for (int r = 0; r < 16; ++r) { oC0[r] *= fs; oC1[r] *= fs; }
    }
#pragma unroll
    for (int r = 0; r < 16; ++r) {
      float pv = EXP2(sC[r] - m_r);
      sC[r] = pv;
      l_r += pv;
    }
    uint32_t u0 = cvtpk(sC[0], sC[1]), u1 = cvtpk(sC[2], sC[3]);
    uint32_t u2 = cvtpk(sC[4], sC[5]), u3 = cvtpk(sC[6], sC[7]);
    uint32_t u4 = cvtpk(sC[8], sC[9]), u5 = cvtpk(sC[10], sC[11]);
    uint32_t u6 = cvtpk(sC[12], sC[13]), u7 = cvtpk(sC[14], sC[15]);
    pl32swap(u0, u2);
    pl32swap(u1, u3);
    pl32swap(u4, u6);
    pl32swap(u5, u7);
    i32x4 pi0 = {(int)u0, (int)u1, (int)u2, (int)u3};
    i32x4 pi1 = {(int)u4, (int)u5, (int)u6, (int)u7};
    bf16x8 pb0 = __builtin_bit_cast(bf16x8, pi0);
    bf16x8 pb1 = __builtin_bit_cast(bf16x8, pi1);

    const bf16* vbase = vrow + j0;
    bf16x8 va00 = *(const bf16x8*)(vbase);
    bf16x8 va01 = *(const bf16x8*)(vbase + 16);
    bf16x8 va10 = *(const bf16x8*)(vbase + 32 * S_LEN);
    bf16x8 va11 = *(const bf16x8*)(vbase + 32 * S_LEN + 16);
    __builtin_amdgcn_s_setprio(1);
    oC0 = MFMA32x32(va00, pb0, oC0);
    oC0 = MFMA32x32(va01, pb1, oC0);
    oC1 = MFMA32x32(va10, pb0, oC1);
    oC1 = MFMA32x32(va11, pb1, oC1);
    __builtin_amdgcn_s_setprio(0);
  }

  {
    uint32_t la = __builtin_bit_cast(uint32_t, l_r), lb = la;
    pl32swap(la, lb);
    l_r = __builtin_bit_cast(float, la) + __builtin_bit_cast(float, lb);
  }
  if (hi == 0) {
    mM[w][ql] = m_r;
    lL[w][ql] = l_r;
  }
#pragma unroll
  for (int r = 0; r < 16; ++r) {
    int d = (r & 3) + 8 * (r >> 2) + 4 * hi;
    oO[w][d][ql] = oC0[r];
    oO[w][d + 32][ql] = oC1[r];
  }
  __syncthreads();

  {
    int mq = t & 31, dbse = (t >> 5) * 8;
    float m0 = mM[0][mq], m1 = mM[1][mq], m2 = mM[2][mq], m3 = mM[3][mq];
    float ms = fmaxf(fmaxf(m0, m1), fmaxf(m2, m3));
    float a0 = EXP2(m0 - ms), a1 = EXP2(m1 - ms), a2 = EXP2(m2 - ms), a3 = EXP2(m3 - ms);
    float ll = a0 * lL[0][mq] + a1 * lL[1][mq] + a2 * lL[2][mq] + a3 * lL[3][mq];
    float inv = 1.0f / ll;
    uint4 pkv;
    uint32_t pw[4];
#pragma unroll
    for (int i = 0; i < 4; ++i) {
      int d0 = dbse + 2 * i, d1 = dbse + 2 * i + 1;
      float e0 = (a0 * oO[0][d0][mq] + a1 * oO[1][d0][mq] + a2 * oO[2][d0][mq] +
                  a3 * oO[3][d0][mq]) * inv;
      float e1 = (a0 * oO[0][d1][mq] + a1 * oO[1][d1][mq] + a2 * oO[2][d1][mq] +
                  a3 * oO[3][d1][mq]) * inv;
      pw[i] = (uint32_t)f2bf(e0) | ((uint32_t)f2bf(e1) << 16);
    }
    pkv.x = pw[0]; pkv.y = pw[1]; pkv.z = pw[2]; pkv.w = pw[3];
    *(uint4*)(ao + (size_t)(qb + mq) * DMODEL + h64 + dbse) = pkv;
  }
}

// ---------------------------------------------------------------------------
extern "C" void kernel_launch(void* const* d_in, const int* in_sizes, int n_in,
                              void* d_out, int out_size, void* d_ws, size_t ws_size,
                              hipStream_t stream) {
  const float* x = (const float*)d_in[0];
  const int* offs = (const int*)d_in[1];
  const float* fcos = (const float*)d_in[2];
  const float* fsin = (const float*)d_in[3];
  const float* ln0g = (const float*)d_in[4];
  const float* ln0b = (const float*)d_in[5];
  const float* ln1g = (const float*)d_in[6];
  const float* ln1b = (const float*)d_in[7];
  const float* wqkv = (const float*)d_in[8];
  const float* bqkv = (const float*)d_in[9];
  const float* wo = (const float*)d_in[10];
  const float* bo = (const float*)d_in[11];
  const float* wu = (const float*)d_in[12];
  const float* bu = (const float*)d_in[13];
  const float* wd = (const float*)d_in[14];
  const float* bd = (const float*)d_in[15];
  const float* lnfg = (const float*)d_in[16];
  const float* lnfb = (const float*)d_in[17];

  char* ws = (char*)d_ws;
  size_t off = 0;
  auto alloc = [&](size_t bytes) -> void* {
    void* p = ws + off;
    off += (bytes + 255) & ~(size_t)255;
    return p;
  };
  bf16* wqkvT = (bf16*)alloc((size_t)NLAYER * 3 * DMODEL * DMODEL * 2);
  bf16* woT = (bf16*)alloc((size_t)NLAYER * DMODEL * DMODEL * 2);
  bf16* wuT = (bf16*)alloc((size_t)NLAYER * DMODEL * FFDIM * 2);
  bf16* wdT = (bf16*)alloc((size_t)NLAYER * FFDIM * DMODEL * 2);
  float* hbuf = (float*)alloc((size_t)S_LEN * DMODEL * 4);
  bf16* ybuf = (bf16*)alloc((size_t)S_LEN * DMODEL * 2);
  bf16* qkv = (bf16*)alloc((size_t)S_LEN * 3 * DMODEL * 2);
  bf16* qrb = (bf16*)alloc((size_t)S_LEN * DMODEL * 2);
  bf16* krb = (bf16*)alloc((size_t)S_LEN * DMODEL * 2);
  bf16* vTb = (bf16*)alloc((size_t)S_LEN * DMODEL * 2);
  bf16* aob = (bf16*)alloc((size_t)S_LEN * DMODEL * 2);
  bf16* midb = (bf16*)alloc((size_t)S_LEN * FFDIM * 2);

  // Split-K partial overlays on DEAD buffers (exact-fit, see analysis):
  //  - WO partials (2 x S*DM fp32 = 16.78 MB) over [qkv, qrb]  (dead after attn)
  //  - DOWN partials (4 x S*DM fp32 = 33.55 MB) over [ybuf .. aob] (all dead)
  float* partWO = (float*)qkv;
  float* partDN = (float*)ybuf;

  for (int ly = 0; ly < NLAYER; ++ly) {
    k_tcast<<<dim3(3 * DMODEL / 32, DMODEL / 32), 256, 0, stream>>>(
        wqkv + (size_t)ly * DMODEL * 3 * DMODEL, wqkvT + (size_t)ly * 3 * DMODEL * DMODEL, DMODEL, 3 * DMODEL);
    k_tcast<<<dim3(DMODEL / 32, DMODEL / 32), 256, 0, stream>>>(
        wo + (size_t)ly * DMODEL * DMODEL, woT + (size_t)ly * DMODEL * DMODEL, DMODEL, DMODEL);
    k_tcast<<<dim3(FFDIM / 32, DMODEL / 32), 256, 0, stream>>>(
        wu + (size_t)ly * DMODEL * FFDIM, wuT + (size_t)ly * DMODEL * FFDIM, DMODEL, FFDIM);
    k_tcast<<<dim3(DMODEL / 32, FFDIM / 32), 256, 0, stream>>>(
        wd + (size_t)ly * FFDIM * DMODEL, wdT + (size_t)ly * FFDIM * DMODEL, FFDIM, DMODEL);
  }
  hipMemcpyAsync(hbuf, x, (size_t)S_LEN * DMODEL * 4, hipMemcpyDeviceToDevice, stream);

  for (int ly = 0; ly < NLAYER; ++ly) {
    k_ln<bf16><<<S_LEN, 256, 0, stream>>>(hbuf, ln0g + ly * DMODEL, ln0b + ly * DMODEL, ybuf);
    // QKV: M=2048, N=3072, K=1024
    k_gemm2<0, 128><<<dim3(S_LEN / 128, 3 * DMODEL / 128, 1), 256, 0, stream>>>(
        ybuf, wqkvT + (size_t)ly * 3 * DMODEL * DMODEL, bqkv + ly * 3 * DMODEL, qkv,
        S_LEN, 3 * DMODEL, DMODEL, DMODEL);
    k_rope<<<S_LEN * NHEAD * 32 / 256, 256, 0, stream>>>(qkv, fcos, fsin, qrb, krb);
    k_tv<<<dim3(S_LEN / 64, NHEAD), 256, 0, stream>>>(qkv, vTb);
    k_attn<<<dim3(NHEAD, S_LEN / 32), 256, 0, stream>>>(qrb, krb, vTb, offs, aob);
    // WO: M=2048, N=1024, K=1024, split-K 2, BM=64 -> 512 blocks
    k_gemm2<3, 64><<<dim3(S_LEN / 64, DMODEL / 128, 2), 256, 0, stream>>>(
        aob, woT + (size_t)ly * DMODEL * DMODEL, nullptr, partWO,
        S_LEN, DMODEL, DMODEL, DMODEL / 2);
    k_reduce<2><<<S_LEN * DMODEL / 1024, 256, 0, stream>>>(
        partWO, bo + ly * DMODEL, hbuf, S_LEN * DMODEL, DMODEL);
    k_ln<bf16><<<S_LEN, 256, 0, stream>>>(hbuf, ln1g + ly * DMODEL, ln1b + ly * DMODEL, ybuf);
    // UP: M=2048, N=4096, K=1024
    k_gemm2<2, 128><<<dim3(S_LEN / 128, FFDIM / 128, 1), 256, 0, stream>>>(
        ybuf, wuT + (size_t)ly * DMODEL * FFDIM, bu + ly * FFDIM, midb,
        S_LEN, FFDIM, DMODEL, DMODEL);
    // DOWN: M=2048, N=1024, K=4096, split-K 4, BM=128 -> 512 blocks
    k_gemm2<3, 128><<<dim3(S_LEN / 128, DMODEL / 128, 4), 256, 0, stream>>>(
        midb, wdT + (size_t)ly * FFDIM * DMODEL, nullptr, partDN,
        S_LEN, DMODEL, FFDIM, FFDIM / 4);
    k_reduce<4><<<S_LEN * DMODEL / 1024, 256, 0, stream>>>(
        partDN, bd + ly * DMODEL, hbuf, S_LEN * DMODEL, DMODEL);
  }
  k_ln<float><<<S_LEN, 256, 0, stream>>>(hbuf, lnfg, lnfb, (float*)d_out);
}

// Round 7
// 408.561 us; speedup vs baseline: 1.5673x; 1.0291x over previous
//
#include <hip/hip_runtime.h>
#include <hip/hip_bf16.h>
#include <stdint.h>
#include <math.h>

#define S_LEN 2048
#define DMODEL 1024
#define NHEAD 16
#define DHEAD 64
#define FFDIM 4096
#define NLAYER 2

using bf16 = __hip_bfloat16;
typedef __attribute__((ext_vector_type(8))) short bf16x8;
typedef __attribute__((ext_vector_type(4))) float f32x4;
typedef __attribute__((ext_vector_type(16))) float f32x16;
typedef __attribute__((ext_vector_type(4))) int i32x4;

#define MFMA16x16(A, B, C) __builtin_amdgcn_mfma_f32_16x16x32_bf16(A, B, C, 0, 0, 0)
#define MFMA32x32(A, B, C) __builtin_amdgcn_mfma_f32_32x32x16_bf16(A, B, C, 0, 0, 0)
#define EXP2(x) __builtin_amdgcn_exp2f(x)

__device__ __forceinline__ float bf2f(uint32_t u16bits) {
  union { uint32_t i; float f; } x;
  x.i = u16bits << 16;
  return x.f;
}
__device__ __forceinline__ uint16_t f2bf(float f) {
  return __builtin_bit_cast(uint16_t, __float2bfloat16(f));
}

// v_cvt_pk_bf16_f32: pack two f32 -> one dword of 2 bf16 (no builtin on gfx950)
__device__ __forceinline__ uint32_t cvtpk(float lo, float hi) {
  uint32_t r;
  asm("v_cvt_pk_bf16_f32 %0, %1, %2" : "=v"(r) : "v"(lo), "v"(hi));
  return r;
}
// v_permlane32_swap_b32
__device__ __forceinline__ void pl32swap(uint32_t& a, uint32_t& b) {
#if __has_builtin(__builtin_amdgcn_permlane32_swap)
  typedef __attribute__((ext_vector_type(2))) int i32x2;
  i32x2 r = __builtin_amdgcn_permlane32_swap((int)a, (int)b, false, false);
  a = (uint32_t)r.x;
  b = (uint32_t)r.y;
#else
  asm volatile("v_permlane32_swap_b32 %0, %1" : "+v"(a), "+v"(b));
#endif
}

// ---------------------------------------------------------------------------
// Weight cast + transpose: in fp32 (R x C)  ->  out bf16 (C x R)
// ---------------------------------------------------------------------------
__global__ __launch_bounds__(256) void k_tcast(const float* __restrict__ in,
                                               bf16* __restrict__ out,
                                               int R, int C) {
  __shared__ float tl[32][33];
  int t = threadIdx.x;
  int r0 = blockIdx.y * 32, c0 = blockIdx.x * 32;
  int cl = t & 31, rl = t >> 5;
#pragma unroll
  for (int i = 0; i < 4; ++i)
    tl[rl + i * 8][cl] = in[(size_t)(r0 + rl + i * 8) * C + c0 + cl];
  __syncthreads();
#pragma unroll
  for (int i = 0; i < 4; ++i)
    out[(size_t)(c0 + rl + i * 8) * R + r0 + cl] = __float2bfloat16(tl[cl][rl + i * 8]);
}

// ---------------------------------------------------------------------------
// LayerNorm over DMODEL=1024
// ---------------------------------------------------------------------------
__device__ __forceinline__ void ln_store4(bf16* p, float a, float b, float c, float d) {
  uint2 u;
  u.x = (uint32_t)f2bf(a) | ((uint32_t)f2bf(b) << 16);
  u.y = (uint32_t)f2bf(c) | ((uint32_t)f2bf(d) << 16);
  *(uint2*)p = u;
}
__device__ __forceinline__ void ln_store4(float* p, float a, float b, float c, float d) {
  *(float4*)p = make_float4(a, b, c, d);
}

template <typename OUT>
__global__ __launch_bounds__(256) void k_ln(const float* __restrict__ h,
                                            const float* __restrict__ g,
                                            const float* __restrict__ b,
                                            OUT* __restrict__ y) {
  int row = blockIdx.x, t = threadIdx.x;
  const float4 v = ((const float4*)(h + (size_t)row * DMODEL))[t];
  float s = v.x + v.y + v.z + v.w;
  float s2 = v.x * v.x + v.y * v.y + v.z * v.z + v.w * v.w;
#pragma unroll
  for (int off = 32; off > 0; off >>= 1) {
    s += __shfl_down(s, off);
    s2 += __shfl_down(s2, off);
  }
  __shared__ float red[8];
  int w = t >> 6;
  if ((t & 63) == 0) { red[w] = s; red[4 + w] = s2; }
  __syncthreads();
  s = red[0] + red[1] + red[2] + red[3];
  s2 = red[4] + red[5] + red[6] + red[7];
  float mean = s * (1.0f / DMODEL);
  float var = s2 * (1.0f / DMODEL) - mean * mean;
  float rstd = rsqrtf(var + 1e-5f);
  float4 gv = ((const float4*)g)[t];
  float4 bv = ((const float4*)b)[t];
  float o0 = (v.x - mean) * rstd * gv.x + bv.x;
  float o1 = (v.y - mean) * rstd * gv.y + bv.y;
  float o2 = (v.z - mean) * rstd * gv.z + bv.z;
  float o3 = (v.w - mean) * rstd * gv.w + bv.w;
  ln_store4(y + (size_t)row * DMODEL + t * 4, o0, o1, o2, o3);
}

// ---------------------------------------------------------------------------
// RoPE on q,k sections of qkv
// ---------------------------------------------------------------------------
__global__ __launch_bounds__(256) void k_rope(const bf16* __restrict__ qkv,
                                              const float* __restrict__ fcos,
                                              const float* __restrict__ fsin,
                                              bf16* __restrict__ qr,
                                              bf16* __restrict__ kr) {
  int idx = blockIdx.x * 256 + threadIdx.x;
  int p = idx & 31;
  int hh = (idx >> 5) & (NHEAD - 1);
  int s = idx >> 9;
  float c = fcos[s * 32 + p], sn = fsin[s * 32 + p];
  int colq = hh * DHEAD + 2 * p;
  uint32_t rq = *(const uint32_t*)(qkv + (size_t)s * 3 * DMODEL + colq);
  uint32_t rk = *(const uint32_t*)(qkv + (size_t)s * 3 * DMODEL + DMODEL + colq);
  {
    float te = bf2f(rq & 0xffffu), to = bf2f(rq >> 16);
    uint32_t outv = (uint32_t)f2bf(te * c - to * sn) | ((uint32_t)f2bf(te * sn + to * c) << 16);
    *(uint32_t*)(qr + (size_t)s * DMODEL + colq) = outv;
  }
  {
    float te = bf2f(rk & 0xffffu), to = bf2f(rk >> 16);
    uint32_t outv = (uint32_t)f2bf(te * c - to * sn) | ((uint32_t)f2bf(te * sn + to * c) << 16);
    *(uint32_t*)(kr + (size_t)s * DMODEL + colq) = outv;
  }
}

// ---------------------------------------------------------------------------
// V transpose per head: vT[h][d][s]
// ---------------------------------------------------------------------------
__global__ __launch_bounds__(256) void k_tv(const bf16* __restrict__ qkv,
                                            bf16* __restrict__ vT) {
  __shared__ bf16 tl[64][65];
  int t = threadIdx.x;
  int hh = blockIdx.y;
  int sb = blockIdx.x * 64;
#pragma unroll
  for (int i = 0; i < 16; ++i) {
    int e = i * 256 + t;
    int sl = e >> 6, d = e & 63;
    tl[sl][d] = qkv[(size_t)(sb + sl) * 3 * DMODEL + 2 * DMODEL + hh * DHEAD + d];
  }
  __syncthreads();
#pragma unroll
  for (int i = 0; i < 16; ++i) {
    int e = i * 256 + t;
    int d = e >> 6, sl = e & 63;
    vT[(size_t)(hh * DHEAD + d) * S_LEN + sb + sl] = tl[sl][d];
  }
}

// ---------------------------------------------------------------------------
// GEMM v3: C[M,N] = A[M,K](bf16) * BT[N,K]^T.  BK=64, XOR-swizzled LDS (T2),
// 2-phase double-buffered prefetch (T3-minimal): STAGE(t+1) issued BEFORE
// ds_read+MFMA of tile t; single __syncthreads (vmcnt drain) per tile, so
// HBM/L2 latency hides under compute. Chunked XCD swizzle (T1) on flat xy
// (all xy-grids divisible by 8). Split-K via blockIdx.z.
// EPI 0: bias -> bf16.  EPI 2: gelu(bias) -> bf16.  EPI 3: raw fp32 partial.
// ---------------------------------------------------------------------------
template <int EPI, int BM>
__global__ __launch_bounds__(256) void k_gemm2(const bf16* __restrict__ A,
                                               const bf16* __restrict__ BT,
                                               const float* __restrict__ bias,
                                               void* __restrict__ out,
                                               int M, int N, int K, int Kc) {
  constexpr int MF = BM / 32;  // m-frags per wave
  __shared__ bf16 As[2][BM * 64];
  __shared__ bf16 Bs[2][128 * 64];
  int t = threadIdx.x;
  int w = t >> 6, l = t & 63, lr = l & 15, lg = l >> 4;

  // T1: chunked XCD swizzle on flattened xy (nxy % 8 == 0 for all launches)
  int nxy = gridDim.x * gridDim.y;
  int bid = blockIdx.y * gridDim.x + blockIdx.x;
  int chk8 = nxy >> 3;
  int swz = (bid & 7) * chk8 + (bid >> 3);
  int bx = swz % gridDim.x, by = swz / gridDim.x;
  int bm = bx * BM, bn = by * 128;
  int k0 = blockIdx.z * Kc;
  int wm = (w >> 1) * (BM / 2), wn = (w & 1) * 64;

  f32x4 zero4 = {0.f, 0.f, 0.f, 0.f};
  f32x4 acc[MF][4];
#pragma unroll
  for (int mf = 0; mf < MF; ++mf)
#pragma unroll
    for (int nf = 0; nf < 4; ++nf) acc[mf][nf] = zero4;

  // stage one 64-wide K-tile into buffer `buf` (pre-swizzled global source)
  auto stage = [&](int buf, int kk) {
#pragma unroll
    for (int i = 0; i < BM / 32; ++i) {
      int chunk = i * 256 + t;
      int row = chunk >> 3;
      int scol = ((chunk ^ row) & 7) << 3;  // (slot ^ (row&7)) * 8
      __builtin_amdgcn_global_load_lds(
          (__attribute__((address_space(1))) void*)(A + (size_t)(bm + row) * K + kk + scol),
          (__attribute__((address_space(3))) void*)(&As[buf][chunk * 8]), 16, 0, 0);
    }
#pragma unroll
    for (int i = 0; i < 4; ++i) {
      int chunk = i * 256 + t;
      int row = chunk >> 3;
      int scol = ((chunk ^ row) & 7) << 3;
      __builtin_amdgcn_global_load_lds(
          (__attribute__((address_space(1))) void*)(BT + (size_t)(bn + row) * K + kk + scol),
          (__attribute__((address_space(3))) void*)(&Bs[buf][chunk * 8]), 16, 0, 0);
    }
  };

  int nt = Kc / 64;
  stage(0, k0);
  __syncthreads();
  int cur = 0;
  for (int kt = 0; kt < nt; ++kt) {
    if (kt + 1 < nt) stage(cur ^ 1, k0 + (kt + 1) * 64);  // prefetch next tile
    bf16x8 af[2][MF], bfr[2][4];
#pragma unroll
    for (int h = 0; h < 2; ++h) {
#pragma unroll
      for (int mf = 0; mf < MF; ++mf) {
        int row = wm + mf * 16 + lr;
        af[h][mf] = *(const bf16x8*)(&As[cur][row * 64 + ((((h << 2) + lg) ^ (row & 7)) << 3)]);
      }
#pragma unroll
      for (int nf = 0; nf < 4; ++nf) {
        int row = wn + nf * 16 + lr;
        bfr[h][nf] = *(const bf16x8*)(&Bs[cur][row * 64 + ((((h << 2) + lg) ^ (row & 7)) << 3)]);
      }
    }
#pragma unroll
    for (int h = 0; h < 2; ++h)
#pragma unroll
      for (int mf = 0; mf < MF; ++mf)
#pragma unroll
        for (int nf = 0; nf < 4; ++nf)
          acc[mf][nf] = MFMA16x16(af[h][mf], bfr[h][nf], acc[mf][nf]);
    __syncthreads();  // drains vmcnt (prefetch landed) + orders buffer reuse
    cur ^= 1;
  }

  if (EPI == 3) {
    float* outf = (float*)out + (size_t)blockIdx.z * ((size_t)M * N);
#pragma unroll
    for (int mf = 0; mf < MF; ++mf)
#pragma unroll
      for (int nf = 0; nf < 4; ++nf) {
        int col = bn + wn + nf * 16 + lr;
        int row0 = bm + wm + mf * 16 + lg * 4;
#pragma unroll
        for (int r = 0; r < 4; ++r)
          outf[(size_t)(row0 + r) * N + col] = acc[mf][nf][r];
      }
  } else {
    bf16* outb = (bf16*)out;
#pragma unroll
    for (int mf = 0; mf < MF; ++mf)
#pragma unroll
      for (int nf = 0; nf < 4; ++nf) {
        int col = bn + wn + nf * 16 + lr;
        float bv = bias[col];
        int row0 = bm + wm + mf * 16 + lg * 4;
#pragma unroll
        for (int r = 0; r < 4; ++r) {
          float v = acc[mf][nf][r] + bv;
          if (EPI == 2)
            v = 0.5f * v * (1.0f + tanhf(0.7978845608028654f * (v + 0.044715f * v * v * v)));
          outb[(size_t)(row0 + r) * N + col] = __float2bfloat16(v);
        }
      }
  }
}

// ---------------------------------------------------------------------------
// Split-K merge: hb = hb + bias + sum_ks part[ks]  (fp32, vectorized x4)
// ---------------------------------------------------------------------------
template <int KS>
__global__ __launch_bounds__(256) void k_reduce(const float* __restrict__ part,
                                                const float* __restrict__ bias,
                                                float* __restrict__ hb,
                                                int MN, int N) {
  int i4 = (blockIdx.x * 256 + threadIdx.x) * 4;
  float4 r = *(const float4*)(hb + i4);
  float4 b = *(const float4*)(bias + (i4 & (N - 1)));
  float sx = r.x + b.x, sy = r.y + b.y, sz = r.z + b.z, sw = r.w + b.w;
#pragma unroll
  for (int ks = 0; ks < KS; ++ks) {
    float4 p = *(const float4*)(part + (size_t)ks * MN + i4);
    sx += p.x; sy += p.y; sz += p.z; sw += p.w;
  }
  *(float4*)(hb + i4) = make_float4(sx, sy, sz, sw);
}

// ---------------------------------------------------------------------------
// Flash attention v4: swapped-operand 32x32x16 MFMA, in-register softmax.
// (unchanged)
// ---------------------------------------------------------------------------
__global__ __launch_bounds__(256, 4) void k_attn(const bf16* __restrict__ qr,
                                                 const bf16* __restrict__ kr,
                                                 const bf16* __restrict__ vT,
                                                 const int* __restrict__ offs,
                                                 bf16* __restrict__ ao) {
  __shared__ float oO[4][64][33];
  __shared__ float mM[4][32];
  __shared__ float lL[4][32];

  int t = threadIdx.x, w = t >> 6, l = t & 63;
  int ql = l & 31, hi = l >> 5, hi8 = hi * 8;
  int hh = blockIdx.x, qb = blockIdx.y * 32;
  int h64 = hh * DHEAD;

  constexpr float LOG2E = 1.4426950408889634f;
  constexpr float C1 = 0.125f * LOG2E;

  int q = qb + ql;
  int o0 = offs[0], o1 = offs[1], o2 = offs[2], o3 = offs[3], o4 = offs[4];
  int sl0 = -1073741824, sh0 = 1073741824;
  sl0 = (o0 <= q) ? o0 : sl0;
  sl0 = (o1 <= q) ? o1 : sl0;
  sl0 = (o2 <= q) ? o2 : sl0;
  sl0 = (o3 <= q) ? o3 : sl0;
  sl0 = (o4 <= q) ? o4 : sl0;
  sh0 = (o4 > q) ? o4 : sh0;
  sh0 = (o3 > q) ? o3 : sh0;
  sh0 = (o2 > q) ? o2 : sh0;
  sh0 = (o1 > q) ? o1 : sh0;
  sh0 = (o0 > q) ? o0 : sh0;
  uint32_t spanu = (uint32_t)(sh0 - sl0);

  const bf16* qbase = qr + (size_t)q * DMODEL + h64 + hi8;
  bf16x8 qf0 = *(const bf16x8*)(qbase);
  bf16x8 qf1 = *(const bf16x8*)(qbase + 16);
  bf16x8 qf2 = *(const bf16x8*)(qbase + 32);
  bf16x8 qf3 = *(const bf16x8*)(qbase + 48);

  f32x16 oC0, oC1;
#pragma unroll
  for (int r = 0; r < 16; ++r) { oC0[r] = 0.f; oC1[r] = 0.f; }
  float m_r = -1e30f, l_r = 0.f;

  const bf16* vrow = vT + (size_t)(h64 + ql) * S_LEN + hi8;

  for (int it = 0; it < 16; ++it) {
    int j0 = w * 512 + it * 32;
    const bf16* kbase = kr + (size_t)(j0 + ql) * DMODEL + h64 + hi8;
    bf16x8 kf0 = *(const bf16x8*)(kbase);
    bf16x8 kf1 = *(const bf16x8*)(kbase + 16);
    bf16x8 kf2 = *(const bf16x8*)(kbase + 32);
    bf16x8 kf3 = *(const bf16x8*)(kbase + 48);
    f32x16 sC;
#pragma unroll
    for (int r = 0; r < 16; ++r) sC[r] = 0.f;
    __builtin_amdgcn_s_setprio(1);
    sC = MFMA32x32(kf0, qf0, sC);
    sC = MFMA32x32(kf1, qf1, sC);
    sC = MFMA32x32(kf2, qf2, sC);
    sC = MFMA32x32(kf3, qf3, sC);
    __builtin_amdgcn_s_setprio(0);

    int tt = j0 + hi * 4 - sl0;
#pragma unroll
    for (int r = 0; r < 16; ++r) {
      int ku = tt + ((r & 3) + 8 * (r >> 2));
      float bias = ((uint32_t)ku < spanu) ? LOG2E : 0.0f;
      sC[r] = sC[r] * C1 + bias;
    }
    float rm = sC[0];
#pragma unroll
    for (int r = 1; r < 16; ++r) rm = fmaxf(rm, sC[r]);
    uint32_t ra = __builtin_bit_cast(uint32_t, rm), rb = ra;
    pl32swap(ra, rb);
    float rmax = fmaxf(__builtin_bit_cast(float, ra), __builtin_bit_cast(float, rb));

    if (__any(rmax > m_r + 8.0f)) {
      float mn = fmaxf(m_r, rmax);
      float fs = EXP2(m_r - mn);
      m_r = mn;
      l_r *= fs;
#pragma unroll
      for (int r = 0; r < 16; ++r) { oC0[r] *= fs; oC1[r] *= fs; }
    }
#pragma unroll
    for (int r = 0; r < 16; ++r) {
      float pv = EXP2(sC[r] - m_r);
      sC[r] = pv;
      l_r += pv;
    }
    uint32_t u0 = cvtpk(sC[0], sC[1]), u1 = cvtpk(sC[2], sC[3]);
    uint32_t u2 = cvtpk(sC[4], sC[5]), u3 = cvtpk(sC[6], sC[7]);
    uint32_t u4 = cvtpk(sC[8], sC[9]), u5 = cvtpk(sC[10], sC[11]);
    uint32_t u6 = cvtpk(sC[12], sC[13]), u7 = cvtpk(sC[14], sC[15]);
    pl32swap(u0, u2);
    pl32swap(u1, u3);
    pl32swap(u4, u6);
    pl32swap(u5, u7);
    i32x4 pi0 = {(int)u0, (int)u1, (int)u2, (int)u3};
    i32x4 pi1 = {(int)u4, (int)u5, (int)u6, (int)u7};
    bf16x8 pb0 = __builtin_bit_cast(bf16x8, pi0);
    bf16x8 pb1 = __builtin_bit_cast(bf16x8, pi1);

    const bf16* vbase = vrow + j0;
    bf16x8 va00 = *(const bf16x8*)(vbase);
    bf16x8 va01 = *(const bf16x8*)(vbase + 16);
    bf16x8 va10 = *(const bf16x8*)(vbase + 32 * S_LEN);
    bf16x8 va11 = *(const bf16x8*)(vbase + 32 * S_LEN + 16);
    __builtin_amdgcn_s_setprio(1);
    oC0 = MFMA32x32(va00, pb0, oC0);
    oC0 = MFMA32x32(va01, pb1, oC0);
    oC1 = MFMA32x32(va10, pb0, oC1);
    oC1 = MFMA32x32(va11, pb1, oC1);
    __builtin_amdgcn_s_setprio(0);
  }

  {
    uint32_t la = __builtin_bit_cast(uint32_t, l_r), lb = la;
    pl32swap(la, lb);
    l_r = __builtin_bit_cast(float, la) + __builtin_bit_cast(float, lb);
  }
  if (hi == 0) {
    mM[w][ql] = m_r;
    lL[w][ql] = l_r;
  }
#pragma unroll
  for (int r = 0; r < 16; ++r) {
    int d = (r & 3) + 8 * (r >> 2) + 4 * hi;
    oO[w][d][ql] = oC0[r];
    oO[w][d + 32][ql] = oC1[r];
  }
  __syncthreads();

  {
    int mq = t & 31, dbse = (t >> 5) * 8;
    float m0 = mM[0][mq], m1 = mM[1][mq], m2 = mM[2][mq], m3 = mM[3][mq];
    float ms = fmaxf(fmaxf(m0, m1), fmaxf(m2, m3));
    float a0 = EXP2(m0 - ms), a1 = EXP2(m1 - ms), a2 = EXP2(m2 - ms), a3 = EXP2(m3 - ms);
    float ll = a0 * lL[0][mq] + a1 * lL[1][mq] + a2 * lL[2][mq] + a3 * lL[3][mq];
    float inv = 1.0f / ll;
    uint4 pkv;
    uint32_t pw[4];
#pragma unroll
    for (int i = 0; i < 4; ++i) {
      int d0 = dbse + 2 * i, d1 = dbse + 2 * i + 1;
      float e0 = (a0 * oO[0][d0][mq] + a1 * oO[1][d0][mq] + a2 * oO[2][d0][mq] +
                  a3 * oO[3][d0][mq]) * inv;
      float e1 = (a0 * oO[0][d1][mq] + a1 * oO[1][d1][mq] + a2 * oO[2][d1][mq] +
                  a3 * oO[3][d1][mq]) * inv;
      pw[i] = (uint32_t)f2bf(e0) | ((uint32_t)f2bf(e1) << 16);
    }
    pkv.x = pw[0]; pkv.y = pw[1]; pkv.z = pw[2]; pkv.w = pw[3];
    *(uint4*)(ao + (size_t)(qb + mq) * DMODEL + h64 + dbse) = pkv;
  }
}

// ---------------------------------------------------------------------------
extern "C" void kernel_launch(void* const* d_in, const int* in_sizes, int n_in,
                              void* d_out, int out_size, void* d_ws, size_t ws_size,
                              hipStream_t stream) {
  const float* x = (const float*)d_in[0];
  const int* offs = (const int*)d_in[1];
  const float* fcos = (const float*)d_in[2];
  const float* fsin = (const float*)d_in[3];
  const float* ln0g = (const float*)d_in[4];
  const float* ln0b = (const float*)d_in[5];
  const float* ln1g = (const float*)d_in[6];
  const float* ln1b = (const float*)d_in[7];
  const float* wqkv = (const float*)d_in[8];
  const float* bqkv = (const float*)d_in[9];
  const float* wo = (const float*)d_in[10];
  const float* bo = (const float*)d_in[11];
  const float* wu = (const float*)d_in[12];
  const float* bu = (const float*)d_in[13];
  const float* wd = (const float*)d_in[14];
  const float* bd = (const float*)d_in[15];
  const float* lnfg = (const float*)d_in[16];
  const float* lnfb = (const float*)d_in[17];

  char* ws = (char*)d_ws;
  size_t off = 0;
  auto alloc = [&](size_t bytes) -> void* {
    void* p = ws + off;
    off += (bytes + 255) & ~(size_t)255;
    return p;
  };
  bf16* wqkvT = (bf16*)alloc((size_t)NLAYER * 3 * DMODEL * DMODEL * 2);
  bf16* woT = (bf16*)alloc((size_t)NLAYER * DMODEL * DMODEL * 2);
  bf16* wuT = (bf16*)alloc((size_t)NLAYER * DMODEL * FFDIM * 2);
  bf16* wdT = (bf16*)alloc((size_t)NLAYER * FFDIM * DMODEL * 2);
  float* hbuf = (float*)alloc((size_t)S_LEN * DMODEL * 4);
  bf16* ybuf = (bf16*)alloc((size_t)S_LEN * DMODEL * 2);
  bf16* qkv = (bf16*)alloc((size_t)S_LEN * 3 * DMODEL * 2);
  bf16* qrb = (bf16*)alloc((size_t)S_LEN * DMODEL * 2);
  bf16* krb = (bf16*)alloc((size_t)S_LEN * DMODEL * 2);
  bf16* vTb = (bf16*)alloc((size_t)S_LEN * DMODEL * 2);
  bf16* aob = (bf16*)alloc((size_t)S_LEN * DMODEL * 2);
  bf16* midb = (bf16*)alloc((size_t)S_LEN * FFDIM * 2);

  // Split-K partial overlays on DEAD buffers (exact-fit):
  //  - WO partials (2 x S*DM fp32 = 16.78 MB) over [qkv, qrb]  (dead after attn)
  //  - DOWN partials (4 x S*DM fp32 = 33.55 MB) over [ybuf .. aob] (all dead)
  float* partWO = (float*)qkv;
  float* partDN = (float*)ybuf;

  for (int ly = 0; ly < NLAYER; ++ly) {
    k_tcast<<<dim3(3 * DMODEL / 32, DMODEL / 32), 256, 0, stream>>>(
        wqkv + (size_t)ly * DMODEL * 3 * DMODEL, wqkvT + (size_t)ly * 3 * DMODEL * DMODEL, DMODEL, 3 * DMODEL);
    k_tcast<<<dim3(DMODEL / 32, DMODEL / 32), 256, 0, stream>>>(
        wo + (size_t)ly * DMODEL * DMODEL, woT + (size_t)ly * DMODEL * DMODEL, DMODEL, DMODEL);
    k_tcast<<<dim3(FFDIM / 32, DMODEL / 32), 256, 0, stream>>>(
        wu + (size_t)ly * DMODEL * FFDIM, wuT + (size_t)ly * DMODEL * FFDIM, DMODEL, FFDIM);
    k_tcast<<<dim3(DMODEL / 32, FFDIM / 32), 256, 0, stream>>>(
        wd + (size_t)ly * FFDIM * DMODEL, wdT + (size_t)ly * FFDIM * DMODEL, FFDIM, DMODEL);
  }
  hipMemcpyAsync(hbuf, x, (size_t)S_LEN * DMODEL * 4, hipMemcpyDeviceToDevice, stream);

  for (int ly = 0; ly < NLAYER; ++ly) {
    k_ln<bf16><<<S_LEN, 256, 0, stream>>>(hbuf, ln0g + ly * DMODEL, ln0b + ly * DMODEL, ybuf);
    // QKV: M=2048, N=3072, K=1024  (grid 16x24 = 384)
    k_gemm2<0, 128><<<dim3(S_LEN / 128, 3 * DMODEL / 128, 1), 256, 0, stream>>>(
        ybuf, wqkvT + (size_t)ly * 3 * DMODEL * DMODEL, bqkv + ly * 3 * DMODEL, qkv,
        S_LEN, 3 * DMODEL, DMODEL, DMODEL);
    k_rope<<<S_LEN * NHEAD * 32 / 256, 256, 0, stream>>>(qkv, fcos, fsin, qrb, krb);
    k_tv<<<dim3(S_LEN / 64, NHEAD), 256, 0, stream>>>(qkv, vTb);
    k_attn<<<dim3(NHEAD, S_LEN / 32), 256, 0, stream>>>(qrb, krb, vTb, offs, aob);
    // WO: M=2048, N=1024, K=1024, split-K 2, BM=64  (xy grid 32x8 = 256)
    k_gemm2<3, 64><<<dim3(S_LEN / 64, DMODEL / 128, 2), 256, 0, stream>>>(
        aob, woT + (size_t)ly * DMODEL * DMODEL, nullptr, partWO,
        S_LEN, DMODEL, DMODEL, DMODEL / 2);
    k_reduce<2><<<S_LEN * DMODEL / 1024, 256, 0, stream>>>(
        partWO, bo + ly * DMODEL, hbuf, S_LEN * DMODEL, DMODEL);
    k_ln<bf16><<<S_LEN, 256, 0, stream>>>(hbuf, ln1g + ly * DMODEL, ln1b + ly * DMODEL, ybuf);
    // UP: M=2048, N=4096, K=1024  (grid 16x32 = 512)
    k_gemm2<2, 128><<<dim3(S_LEN / 128, FFDIM / 128, 1), 256, 0, stream>>>(
        ybuf, wuT + (size_t)ly * DMODEL * FFDIM, bu + ly * FFDIM, midb,
        S_LEN, FFDIM, DMODEL, DMODEL);
    // DOWN: M=2048, N=1024, K=4096, split-K 4, BM=128  (xy grid 16x8 = 128)
    k_gemm2<3, 128><<<dim3(S_LEN / 128, DMODEL / 128, 4), 256, 0, stream>>>(
        midb, wdT + (size_t)ly * FFDIM * DMODEL, nullptr, partDN,
        S_LEN, DMODEL, FFDIM, FFDIM / 4);
    k_reduce<4><<<S_LEN * DMODEL / 1024, 256, 0, stream>>>(
        partDN, bd + ly * DMODEL, hbuf, S_LEN * DMODEL, DMODEL);
  }
  k_ln<float><<<S_LEN, 256, 0, stream>>>(hbuf, lnfg, lnfb, (float*)d_out);
}

// Round 8
// 407.027 us; speedup vs baseline: 1.5733x; 1.0038x over previous
//
#include <hip/hip_runtime.h>
#include <hip/hip_bf16.h>
#include <stdint.h>
#include <math.h>

#define S_LEN 2048
#define DMODEL 1024
#define NHEAD 16
#define DHEAD 64
#define FFDIM 4096
#define NLAYER 2

using bf16 = __hip_bfloat16;
typedef __attribute__((ext_vector_type(8))) short bf16x8;
typedef __attribute__((ext_vector_type(4))) float f32x4;
typedef __attribute__((ext_vector_type(16))) float f32x16;
typedef __attribute__((ext_vector_type(4))) int i32x4;

#define MFMA16x16(A, B, C) __builtin_amdgcn_mfma_f32_16x16x32_bf16(A, B, C, 0, 0, 0)
#define MFMA32x32(A, B, C) __builtin_amdgcn_mfma_f32_32x32x16_bf16(A, B, C, 0, 0, 0)
#define EXP2(x) __builtin_amdgcn_exp2f(x)

__device__ __forceinline__ float bf2f(uint32_t u16bits) {
  union { uint32_t i; float f; } x;
  x.i = u16bits << 16;
  return x.f;
}
__device__ __forceinline__ uint16_t f2bf(float f) {
  return __builtin_bit_cast(uint16_t, __float2bfloat16(f));
}

// v_cvt_pk_bf16_f32: pack two f32 -> one dword of 2 bf16 (no builtin on gfx950)
__device__ __forceinline__ uint32_t cvtpk(float lo, float hi) {
  uint32_t r;
  asm("v_cvt_pk_bf16_f32 %0, %1, %2" : "=v"(r) : "v"(lo), "v"(hi));
  return r;
}
// v_permlane32_swap_b32
__device__ __forceinline__ void pl32swap(uint32_t& a, uint32_t& b) {
#if __has_builtin(__builtin_amdgcn_permlane32_swap)
  typedef __attribute__((ext_vector_type(2))) int i32x2;
  i32x2 r = __builtin_amdgcn_permlane32_swap((int)a, (int)b, false, false);
  a = (uint32_t)r.x;
  b = (uint32_t)r.y;
#else
  asm volatile("v_permlane32_swap_b32 %0, %1" : "+v"(a), "+v"(b));
#endif
}

// ---------------------------------------------------------------------------
// Weight cast + transpose: in fp32 (R x C)  ->  out bf16 (C x R)
// ---------------------------------------------------------------------------
__global__ __launch_bounds__(256) void k_tcast(const float* __restrict__ in,
                                               bf16* __restrict__ out,
                                               int R, int C) {
  __shared__ float tl[32][33];
  int t = threadIdx.x;
  int r0 = blockIdx.y * 32, c0 = blockIdx.x * 32;
  int cl = t & 31, rl = t >> 5;
#pragma unroll
  for (int i = 0; i < 4; ++i)
    tl[rl + i * 8][cl] = in[(size_t)(r0 + rl + i * 8) * C + c0 + cl];
  __syncthreads();
#pragma unroll
  for (int i = 0; i < 4; ++i)
    out[(size_t)(c0 + rl + i * 8) * R + r0 + cl] = __float2bfloat16(tl[cl][rl + i * 8]);
}

// ---------------------------------------------------------------------------
// LayerNorm over DMODEL=1024
// ---------------------------------------------------------------------------
__device__ __forceinline__ void ln_store4(bf16* p, float a, float b, float c, float d) {
  uint2 u;
  u.x = (uint32_t)f2bf(a) | ((uint32_t)f2bf(b) << 16);
  u.y = (uint32_t)f2bf(c) | ((uint32_t)f2bf(d) << 16);
  *(uint2*)p = u;
}
__device__ __forceinline__ void ln_store4(float* p, float a, float b, float c, float d) {
  *(float4*)p = make_float4(a, b, c, d);
}

template <typename OUT>
__global__ __launch_bounds__(256) void k_ln(const float* __restrict__ h,
                                            const float* __restrict__ g,
                                            const float* __restrict__ b,
                                            OUT* __restrict__ y) {
  int row = blockIdx.x, t = threadIdx.x;
  const float4 v = ((const float4*)(h + (size_t)row * DMODEL))[t];
  float s = v.x + v.y + v.z + v.w;
  float s2 = v.x * v.x + v.y * v.y + v.z * v.z + v.w * v.w;
#pragma unroll
  for (int off = 32; off > 0; off >>= 1) {
    s += __shfl_down(s, off);
    s2 += __shfl_down(s2, off);
  }
  __shared__ float red[8];
  int w = t >> 6;
  if ((t & 63) == 0) { red[w] = s; red[4 + w] = s2; }
  __syncthreads();
  s = red[0] + red[1] + red[2] + red[3];
  s2 = red[4] + red[5] + red[6] + red[7];
  float mean = s * (1.0f / DMODEL);
  float var = s2 * (1.0f / DMODEL) - mean * mean;
  float rstd = rsqrtf(var + 1e-5f);
  float4 gv = ((const float4*)g)[t];
  float4 bv = ((const float4*)b)[t];
  float o0 = (v.x - mean) * rstd * gv.x + bv.x;
  float o1 = (v.y - mean) * rstd * gv.y + bv.y;
  float o2 = (v.z - mean) * rstd * gv.z + bv.z;
  float o3 = (v.w - mean) * rstd * gv.w + bv.w;
  ln_store4(y + (size_t)row * DMODEL + t * 4, o0, o1, o2, o3);
}

// ---------------------------------------------------------------------------
// RoPE on q,k sections of qkv
// ---------------------------------------------------------------------------
__global__ __launch_bounds__(256) void k_rope(const bf16* __restrict__ qkv,
                                              const float* __restrict__ fcos,
                                              const float* __restrict__ fsin,
                                              bf16* __restrict__ qr,
                                              bf16* __restrict__ kr) {
  int idx = blockIdx.x * 256 + threadIdx.x;
  int p = idx & 31;
  int hh = (idx >> 5) & (NHEAD - 1);
  int s = idx >> 9;
  float c = fcos[s * 32 + p], sn = fsin[s * 32 + p];
  int colq = hh * DHEAD + 2 * p;
  uint32_t rq = *(const uint32_t*)(qkv + (size_t)s * 3 * DMODEL + colq);
  uint32_t rk = *(const uint32_t*)(qkv + (size_t)s * 3 * DMODEL + DMODEL + colq);
  {
    float te = bf2f(rq & 0xffffu), to = bf2f(rq >> 16);
    uint32_t outv = (uint32_t)f2bf(te * c - to * sn) | ((uint32_t)f2bf(te * sn + to * c) << 16);
    *(uint32_t*)(qr + (size_t)s * DMODEL + colq) = outv;
  }
  {
    float te = bf2f(rk & 0xffffu), to = bf2f(rk >> 16);
    uint32_t outv = (uint32_t)f2bf(te * c - to * sn) | ((uint32_t)f2bf(te * sn + to * c) << 16);
    *(uint32_t*)(kr + (size_t)s * DMODEL + colq) = outv;
  }
}

// ---------------------------------------------------------------------------
// V transpose per head: vT[h][d][s]
// ---------------------------------------------------------------------------
__global__ __launch_bounds__(256) void k_tv(const bf16* __restrict__ qkv,
                                            bf16* __restrict__ vT) {
  __shared__ bf16 tl[64][65];
  int t = threadIdx.x;
  int hh = blockIdx.y;
  int sb = blockIdx.x * 64;
#pragma unroll
  for (int i = 0; i < 16; ++i) {
    int e = i * 256 + t;
    int sl = e >> 6, d = e & 63;
    tl[sl][d] = qkv[(size_t)(sb + sl) * 3 * DMODEL + 2 * DMODEL + hh * DHEAD + d];
  }
  __syncthreads();
#pragma unroll
  for (int i = 0; i < 16; ++i) {
    int e = i * 256 + t;
    int d = e >> 6, sl = e & 63;
    vT[(size_t)(hh * DHEAD + d) * S_LEN + sb + sl] = tl[sl][d];
  }
}

// ---------------------------------------------------------------------------
// GEMM v4: C[M,N] = A[M,K](bf16) * BT[N,K]^T.  BK=64, XOR-swizzled LDS (T2),
// 2-phase double-buffer with CORRECT issue order (T3-minimal, m248):
//   per tile: ds_read(cur) -> stage(next into cur^1) -> MFMA -> barrier.
// ds_reads are issued at vmcnt=0 (previous barrier drained), so the compiler
// emits no vmcnt wait before them; the drain before the barrier lands AFTER
// ds_read+MFMA, hiding the staged-load latency. sched_barrier(0) pins order.
// Chunked XCD swizzle (T1). Split-K via blockIdx.z.
// EPI 0: bias -> bf16.  EPI 2: gelu(bias) -> bf16.  EPI 3: raw fp32 partial.
// ---------------------------------------------------------------------------
template <int EPI, int BM>
__global__ __launch_bounds__(256) void k_gemm2(const bf16* __restrict__ A,
                                               const bf16* __restrict__ BT,
                                               const float* __restrict__ bias,
                                               void* __restrict__ out,
                                               int M, int N, int K, int Kc) {
  constexpr int MF = BM / 32;  // m-frags per wave
  __shared__ bf16 As[2][BM * 64];
  __shared__ bf16 Bs[2][128 * 64];
  int t = threadIdx.x;
  int w = t >> 6, l = t & 63, lr = l & 15, lg = l >> 4;

  // T1: chunked XCD swizzle on flattened xy (nxy % 8 == 0 for all launches)
  int nxy = gridDim.x * gridDim.y;
  int bid = blockIdx.y * gridDim.x + blockIdx.x;
  int chk8 = nxy >> 3;
  int swz = (bid & 7) * chk8 + (bid >> 3);
  int bx = swz % gridDim.x, by = swz / gridDim.x;
  int bm = bx * BM, bn = by * 128;
  int k0 = blockIdx.z * Kc;
  int wm = (w >> 1) * (BM / 2), wn = (w & 1) * 64;

  f32x4 zero4 = {0.f, 0.f, 0.f, 0.f};
  f32x4 acc[MF][4];
#pragma unroll
  for (int mf = 0; mf < MF; ++mf)
#pragma unroll
    for (int nf = 0; nf < 4; ++nf) acc[mf][nf] = zero4;

  // stage one 64-wide K-tile into buffer `buf` (pre-swizzled global source)
  auto stage = [&](int buf, int kk) {
#pragma unroll
    for (int i = 0; i < BM / 32; ++i) {
      int chunk = i * 256 + t;
      int row = chunk >> 3;
      int scol = ((chunk ^ row) & 7) << 3;  // (slot ^ (row&7)) * 8
      __builtin_amdgcn_global_load_lds(
          (__attribute__((address_space(1))) void*)(A + (size_t)(bm + row) * K + kk + scol),
          (__attribute__((address_space(3))) void*)(&As[buf][chunk * 8]), 16, 0, 0);
    }
#pragma unroll
    for (int i = 0; i < 4; ++i) {
      int chunk = i * 256 + t;
      int row = chunk >> 3;
      int scol = ((chunk ^ row) & 7) << 3;
      __builtin_amdgcn_global_load_lds(
          (__attribute__((address_space(1))) void*)(BT + (size_t)(bn + row) * K + kk + scol),
          (__attribute__((address_space(3))) void*)(&Bs[buf][chunk * 8]), 16, 0, 0);
    }
  };

  int nt = Kc / 64;
  stage(0, k0);
  __syncthreads();
  int cur = 0;
  for (int kt = 0; kt < nt; ++kt) {
    // 1) ds_read fragments of the CURRENT buffer first: vmcnt==0 here
    //    (previous __syncthreads drained), so no spurious vmcnt wait.
    bf16x8 af[2][MF], bfr[2][4];
#pragma unroll
    for (int h = 0; h < 2; ++h) {
#pragma unroll
      for (int mf = 0; mf < MF; ++mf) {
        int row = wm + mf * 16 + lr;
        af[h][mf] = *(const bf16x8*)(&As[cur][row * 64 + ((((h << 2) + lg) ^ (row & 7)) << 3)]);
      }
#pragma unroll
      for (int nf = 0; nf < 4; ++nf) {
        int row = wn + nf * 16 + lr;
        bfr[h][nf] = *(const bf16x8*)(&Bs[cur][row * 64 + ((((h << 2) + lg) ^ (row & 7)) << 3)]);
      }
    }
    __builtin_amdgcn_sched_barrier(0);
    // 2) issue next tile's staging (other buffer; safe: cur^1 was last read
    //    before the previous barrier)
    if (kt + 1 < nt) stage(cur ^ 1, k0 + (kt + 1) * 64);
    __builtin_amdgcn_sched_barrier(0);
    // 3) MFMA on registers (waits lgkm only); staged loads fly underneath
#pragma unroll
    for (int h = 0; h < 2; ++h)
#pragma unroll
      for (int mf = 0; mf < MF; ++mf)
#pragma unroll
        for (int nf = 0; nf < 4; ++nf)
          acc[mf][nf] = MFMA16x16(af[h][mf], bfr[h][nf], acc[mf][nf]);
    // 4) drain (vmcnt0+lgkm0) + barrier: prefetch has had the whole compute
    //    phase to complete
    __syncthreads();
    cur ^= 1;
  }

  if (EPI == 3) {
    float* outf = (float*)out + (size_t)blockIdx.z * ((size_t)M * N);
#pragma unroll
    for (int mf = 0; mf < MF; ++mf)
#pragma unroll
      for (int nf = 0; nf < 4; ++nf) {
        int col = bn + wn + nf * 16 + lr;
        int row0 = bm + wm + mf * 16 + lg * 4;
#pragma unroll
        for (int r = 0; r < 4; ++r)
          outf[(size_t)(row0 + r) * N + col] = acc[mf][nf][r];
      }
  } else {
    bf16* outb = (bf16*)out;
#pragma unroll
    for (int mf = 0; mf < MF; ++mf)
#pragma unroll
      for (int nf = 0; nf < 4; ++nf) {
        int col = bn + wn + nf * 16 + lr;
        float bv = bias[col];
        int row0 = bm + wm + mf * 16 + lg * 4;
#pragma unroll
        for (int r = 0; r < 4; ++r) {
          float v = acc[mf][nf][r] + bv;
          if (EPI == 2)
            v = 0.5f * v * (1.0f + tanhf(0.7978845608028654f * (v + 0.044715f * v * v * v)));
          outb[(size_t)(row0 + r) * N + col] = __float2bfloat16(v);
        }
      }
  }
}

// ---------------------------------------------------------------------------
// Split-K merge: hb = hb + bias + sum_ks part[ks]  (fp32, vectorized x4)
// ---------------------------------------------------------------------------
template <int KS>
__global__ __launch_bounds__(256) void k_reduce(const float* __restrict__ part,
                                                const float* __restrict__ bias,
                                                float* __restrict__ hb,
                                                int MN, int N) {
  int i4 = (blockIdx.x * 256 + threadIdx.x) * 4;
  float4 r = *(const float4*)(hb + i4);
  float4 b = *(const float4*)(bias + (i4 & (N - 1)));
  float sx = r.x + b.x, sy = r.y + b.y, sz = r.z + b.z, sw = r.w + b.w;
#pragma unroll
  for (int ks = 0; ks < KS; ++ks) {
    float4 p = *(const float4*)(part + (size_t)ks * MN + i4);
    sx += p.x; sy += p.y; sz += p.z; sw += p.w;
  }
  *(float4*)(hb + i4) = make_float4(sx, sy, sz, sw);
}

// ---------------------------------------------------------------------------
// Flash attention v4: swapped-operand 32x32x16 MFMA, in-register softmax.
// (unchanged)
// ---------------------------------------------------------------------------
__global__ __launch_bounds__(256, 4) void k_attn(const bf16* __restrict__ qr,
                                                 const bf16* __restrict__ kr,
                                                 const bf16* __restrict__ vT,
                                                 const int* __restrict__ offs,
                                                 bf16* __restrict__ ao) {
  __shared__ float oO[4][64][33];
  __shared__ float mM[4][32];
  __shared__ float lL[4][32];

  int t = threadIdx.x, w = t >> 6, l = t & 63;
  int ql = l & 31, hi = l >> 5, hi8 = hi * 8;
  int hh = blockIdx.x, qb = blockIdx.y * 32;
  int h64 = hh * DHEAD;

  constexpr float LOG2E = 1.4426950408889634f;
  constexpr float C1 = 0.125f * LOG2E;

  int q = qb + ql;
  int o0 = offs[0], o1 = offs[1], o2 = offs[2], o3 = offs[3], o4 = offs[4];
  int sl0 = -1073741824, sh0 = 1073741824;
  sl0 = (o0 <= q) ? o0 : sl0;
  sl0 = (o1 <= q) ? o1 : sl0;
  sl0 = (o2 <= q) ? o2 : sl0;
  sl0 = (o3 <= q) ? o3 : sl0;
  sl0 = (o4 <= q) ? o4 : sl0;
  sh0 = (o4 > q) ? o4 : sh0;
  sh0 = (o3 > q) ? o3 : sh0;
  sh0 = (o2 > q) ? o2 : sh0;
  sh0 = (o1 > q) ? o1 : sh0;
  sh0 = (o0 > q) ? o0 : sh0;
  uint32_t spanu = (uint32_t)(sh0 - sl0);

  const bf16* qbase = qr + (size_t)q * DMODEL + h64 + hi8;
  bf16x8 qf0 = *(const bf16x8*)(qbase);
  bf16x8 qf1 = *(const bf16x8*)(qbase + 16);
  bf16x8 qf2 = *(const bf16x8*)(qbase + 32);
  bf16x8 qf3 = *(const bf16x8*)(qbase + 48);

  f32x16 oC0, oC1;
#pragma unroll
  for (int r = 0; r < 16; ++r) { oC0[r] = 0.f; oC1[r] = 0.f; }
  float m_r = -1e30f, l_r = 0.f;

  const bf16* vrow = vT + (size_t)(h64 + ql) * S_LEN + hi8;

  for (int it = 0; it < 16; ++it) {
    int j0 = w * 512 + it * 32;
    const bf16* kbase = kr + (size_t)(j0 + ql) * DMODEL + h64 + hi8;
    bf16x8 kf0 = *(const bf16x8*)(kbase);
    bf16x8 kf1 = *(const bf16x8*)(kbase + 16);
    bf16x8 kf2 = *(const bf16x8*)(kbase + 32);
    bf16x8 kf3 = *(const bf16x8*)(kbase + 48);
    f32x16 sC;
#pragma unroll
    for (int r = 0; r < 16; ++r) sC[r] = 0.f;
    __builtin_amdgcn_s_setprio(1);
    sC = MFMA32x32(kf0, qf0, sC);
    sC = MFMA32x32(kf1, qf1, sC);
    sC = MFMA32x32(kf2, qf2, sC);
    sC = MFMA32x32(kf3, qf3, sC);
    __builtin_amdgcn_s_setprio(0);

    int tt = j0 + hi * 4 - sl0;
#pragma unroll
    for (int r = 0; r < 16; ++r) {
      int ku = tt + ((r & 3) + 8 * (r >> 2));
      float bias = ((uint32_t)ku < spanu) ? LOG2E : 0.0f;
      sC[r] = sC[r] * C1 + bias;
    }
    float rm = sC[0];
#pragma unroll
    for (int r = 1; r < 16; ++r) rm = fmaxf(rm, sC[r]);
    uint32_t ra = __builtin_bit_cast(uint32_t, rm), rb = ra;
    pl32swap(ra, rb);
    float rmax = fmaxf(__builtin_bit_cast(float, ra), __builtin_bit_cast(float, rb));

    if (__any(rmax > m_r + 8.0f)) {
      float mn = fmaxf(m_r, rmax);
      float fs = EXP2(m_r - mn);
      m_r = mn;
      l_r *= fs;
#pragma unroll
      for (int r = 0; r < 16; ++r) { oC0[r] *= fs; oC1[r] *= fs; }
    }
#pragma unroll
    for (int r = 0; r < 16; ++r) {
      float pv = EXP2(sC[r] - m_r);
      sC[r] = pv;
      l_r += pv;
    }
    uint32_t u0 = cvtpk(sC[0], sC[1]), u1 = cvtpk(sC[2], sC[3]);
    uint32_t u2 = cvtpk(sC[4], sC[5]), u3 = cvtpk(sC[6], sC[7]);
    uint32_t u4 = cvtpk(sC[8], sC[9]), u5 = cvtpk(sC[10], sC[11]);
    uint32_t u6 = cvtpk(sC[12], sC[13]), u7 = cvtpk(sC[14], sC[15]);
    pl32swap(u0, u2);
    pl32swap(u1, u3);
    pl32swap(u4, u6);
    pl32swap(u5, u7);
    i32x4 pi0 = {(int)u0, (int)u1, (int)u2, (int)u3};
    i32x4 pi1 = {(int)u4, (int)u5, (int)u6, (int)u7};
    bf16x8 pb0 = __builtin_bit_cast(bf16x8, pi0);
    bf16x8 pb1 = __builtin_bit_cast(bf16x8, pi1);

    const bf16* vbase = vrow + j0;
    bf16x8 va00 = *(const bf16x8*)(vbase);
    bf16x8 va01 = *(const bf16x8*)(vbase + 16);
    bf16x8 va10 = *(const bf16x8*)(vbase + 32 * S_LEN);
    bf16x8 va11 = *(const bf16x8*)(vbase + 32 * S_LEN + 16);
    __builtin_amdgcn_s_setprio(1);
    oC0 = MFMA32x32(va00, pb0, oC0);
    oC0 = MFMA32x32(va01, pb1, oC0);
    oC1 = MFMA32x32(va10, pb0, oC1);
    oC1 = MFMA32x32(va11, pb1, oC1);
    __builtin_amdgcn_s_setprio(0);
  }

  {
    uint32_t la = __builtin_bit_cast(uint32_t, l_r), lb = la;
    pl32swap(la, lb);
    l_r = __builtin_bit_cast(float, la) + __builtin_bit_cast(float, lb);
  }
  if (hi == 0) {
    mM[w][ql] = m_r;
    lL[w][ql] = l_r;
  }
#pragma unroll
  for (int r = 0; r < 16; ++r) {
    int d = (r & 3) + 8 * (r >> 2) + 4 * hi;
    oO[w][d][ql] = oC0[r];
    oO[w][d + 32][ql] = oC1[r];
  }
  __syncthreads();

  {
    int mq = t & 31, dbse = (t >> 5) * 8;
    float m0 = mM[0][mq], m1 = mM[1][mq], m2 = mM[2][mq], m3 = mM[3][mq];
    float ms = fmaxf(fmaxf(m0, m1), fmaxf(m2, m3));
    float a0 = EXP2(m0 - ms), a1 = EXP2(m1 - ms), a2 = EXP2(m2 - ms), a3 = EXP2(m3 - ms);
    float ll = a0 * lL[0][mq] + a1 * lL[1][mq] + a2 * lL[2][mq] + a3 * lL[3][mq];
    float inv = 1.0f / ll;
    uint4 pkv;
    uint32_t pw[4];
#pragma unroll
    for (int i = 0; i < 4; ++i) {
      int d0 = dbse + 2 * i, d1 = dbse + 2 * i + 1;
      float e0 = (a0 * oO[0][d0][mq] + a1 * oO[1][d0][mq] + a2 * oO[2][d0][mq] +
                  a3 * oO[3][d0][mq]) * inv;
      float e1 = (a0 * oO[0][d1][mq] + a1 * oO[1][d1][mq] + a2 * oO[2][d1][mq] +
                  a3 * oO[3][d1][mq]) * inv;
      pw[i] = (uint32_t)f2bf(e0) | ((uint32_t)f2bf(e1) << 16);
    }
    pkv.x = pw[0]; pkv.y = pw[1]; pkv.z = pw[2]; pkv.w = pw[3];
    *(uint4*)(ao + (size_t)(qb + mq) * DMODEL + h64 + dbse) = pkv;
  }
}

// ---------------------------------------------------------------------------
extern "C" void kernel_launch(void* const* d_in, const int* in_sizes, int n_in,
                              void* d_out, int out_size, void* d_ws, size_t ws_size,
                              hipStream_t stream) {
  const float* x = (const float*)d_in[0];
  const int* offs = (const int*)d_in[1];
  const float* fcos = (const float*)d_in[2];
  const float* fsin = (const float*)d_in[3];
  const float* ln0g = (const float*)d_in[4];
  const float* ln0b = (const float*)d_in[5];
  const float* ln1g = (const float*)d_in[6];
  const float* ln1b = (const float*)d_in[7];
  const float* wqkv = (const float*)d_in[8];
  const float* bqkv = (const float*)d_in[9];
  const float* wo = (const float*)d_in[10];
  const float* bo = (const float*)d_in[11];
  const float* wu = (const float*)d_in[12];
  const float* bu = (const float*)d_in[13];
  const float* wd = (const float*)d_in[14];
  const float* bd = (const float*)d_in[15];
  const float* lnfg = (const float*)d_in[16];
  const float* lnfb = (const float*)d_in[17];

  char* ws = (char*)d_ws;
  size_t off = 0;
  auto alloc = [&](size_t bytes) -> void* {
    void* p = ws + off;
    off += (bytes + 255) & ~(size_t)255;
    return p;
  };
  bf16* wqkvT = (bf16*)alloc((size_t)NLAYER * 3 * DMODEL * DMODEL * 2);
  bf16* woT = (bf16*)alloc((size_t)NLAYER * DMODEL * DMODEL * 2);
  bf16* wuT = (bf16*)alloc((size_t)NLAYER * DMODEL * FFDIM * 2);
  bf16* wdT = (bf16*)alloc((size_t)NLAYER * FFDIM * DMODEL * 2);
  float* hbuf = (float*)alloc((size_t)S_LEN * DMODEL * 4);
  bf16* ybuf = (bf16*)alloc((size_t)S_LEN * DMODEL * 2);
  bf16* qkv = (bf16*)alloc((size_t)S_LEN * 3 * DMODEL * 2);
  bf16* qrb = (bf16*)alloc((size_t)S_LEN * DMODEL * 2);
  bf16* krb = (bf16*)alloc((size_t)S_LEN * DMODEL * 2);
  bf16* vTb = (bf16*)alloc((size_t)S_LEN * DMODEL * 2);
  bf16* aob = (bf16*)alloc((size_t)S_LEN * DMODEL * 2);
  bf16* midb = (bf16*)alloc((size_t)S_LEN * FFDIM * 2);

  // Split-K partial overlays on DEAD buffers (exact-fit):
  //  - WO partials (2 x S*DM fp32 = 16.78 MB) over [qkv, qrb]  (dead after attn)
  //  - DOWN partials (4 x S*DM fp32 = 33.55 MB) over [ybuf .. aob] (all dead)
  float* partWO = (float*)qkv;
  float* partDN = (float*)ybuf;

  for (int ly = 0; ly < NLAYER; ++ly) {
    k_tcast<<<dim3(3 * DMODEL / 32, DMODEL / 32), 256, 0, stream>>>(
        wqkv + (size_t)ly * DMODEL * 3 * DMODEL, wqkvT + (size_t)ly * 3 * DMODEL * DMODEL, DMODEL, 3 * DMODEL);
    k_tcast<<<dim3(DMODEL / 32, DMODEL / 32), 256, 0, stream>>>(
        wo + (size_t)ly * DMODEL * DMODEL, woT + (size_t)ly * DMODEL * DMODEL, DMODEL, DMODEL);
    k_tcast<<<dim3(FFDIM / 32, DMODEL / 32), 256, 0, stream>>>(
        wu + (size_t)ly * DMODEL * FFDIM, wuT + (size_t)ly * DMODEL * FFDIM, DMODEL, FFDIM);
    k_tcast<<<dim3(DMODEL / 32, FFDIM / 32), 256, 0, stream>>>(
        wd + (size_t)ly * FFDIM * DMODEL, wdT + (size_t)ly * FFDIM * DMODEL, FFDIM, DMODEL);
  }
  hipMemcpyAsync(hbuf, x, (size_t)S_LEN * DMODEL * 4, hipMemcpyDeviceToDevice, stream);

  for (int ly = 0; ly < NLAYER; ++ly) {
    k_ln<bf16><<<S_LEN, 256, 0, stream>>>(hbuf, ln0g + ly * DMODEL, ln0b + ly * DMODEL, ybuf);
    // QKV: M=2048, N=3072, K=1024  (grid 16x24 = 384)
    k_gemm2<0, 128><<<dim3(S_LEN / 128, 3 * DMODEL / 128, 1), 256, 0, stream>>>(
        ybuf, wqkvT + (size_t)ly * 3 * DMODEL * DMODEL, bqkv + ly * 3 * DMODEL, qkv,
        S_LEN, 3 * DMODEL, DMODEL, DMODEL);
    k_rope<<<S_LEN * NHEAD * 32 / 256, 256, 0, stream>>>(qkv, fcos, fsin, qrb, krb);
    k_tv<<<dim3(S_LEN / 64, NHEAD), 256, 0, stream>>>(qkv, vTb);
    k_attn<<<dim3(NHEAD, S_LEN / 32), 256, 0, stream>>>(qrb, krb, vTb, offs, aob);
    // WO: M=2048, N=1024, K=1024, split-K 2, BM=64  (xy grid 32x8 = 256)
    k_gemm2<3, 64><<<dim3(S_LEN / 64, DMODEL / 128, 2), 256, 0, stream>>>(
        aob, woT + (size_t)ly * DMODEL * DMODEL, nullptr, partWO,
        S_LEN, DMODEL, DMODEL, DMODEL / 2);
    k_reduce<2><<<S_LEN * DMODEL / 1024, 256, 0, stream>>>(
        partWO, bo + ly * DMODEL, hbuf, S_LEN * DMODEL, DMODEL);
    k_ln<bf16><<<S_LEN, 256, 0, stream>>>(hbuf, ln1g + ly * DMODEL, ln1b + ly * DMODEL, ybuf);
    // UP: M=2048, N=4096, K=1024  (grid 16x32 = 512)
    k_gemm2<2, 128><<<dim3(S_LEN / 128, FFDIM / 128, 1), 256, 0, stream>>>(
        ybuf, wuT + (size_t)ly * DMODEL * FFDIM, bu + ly * FFDIM, midb,
        S_LEN, FFDIM, DMODEL, DMODEL);
    // DOWN: M=2048, N=1024, K=4096, split-K 4, BM=128  (xy grid 16x8 = 128)
    k_gemm2<3, 128><<<dim3(S_LEN / 128, DMODEL / 128, 4), 256, 0, stream>>>(
        midb, wdT + (size_t)ly * FFDIM * DMODEL, nullptr, partDN,
        S_LEN, DMODEL, FFDIM, FFDIM / 4);
    k_reduce<4><<<S_LEN * DMODEL / 1024, 256, 0, stream>>>(
        partDN, bd + ly * DMODEL, hbuf, S_LEN * DMODEL, DMODEL);
  }
  k_ln<float><<<S_LEN, 256, 0, stream>>>(hbuf, lnfg, lnfb, (float*)d_out);
}